// Round 2
// baseline (322.281 us; speedup 1.0000x reference)
//
#include <hip/hip_runtime.h>
#include <math.h>

// Problem constants
#define TOKENS 32768
#define DM 4096
#define NE 64
#define BALW 0.1f

#define TG 64
#define GBLOCKS (TOKENS / TG)  // 512

// ================= Kernel A: 256x64 tile, 8x8/thread, BK=16 double-buffered ==
// grid = (TOKENS/TM) * SK. SK=4 -> 512 blocks -> 2 blocks/CU, 8 waves/CU.
// Pipeline: one barrier per 16-k chunk; stores (tile i+1) + global loads
// (tile i+2) issue BEFORE compute on tile i, hiding under 1024 FMAs.
// As k-major [16][260], Ws k-major [16][68], both double-buffered (42 KB).
// Staging stores: bank = 16*(tid&3)+4c+tS -> exactly 2-way (free).
// Frag reads: 2+2 ds_read_b128, 8-lane broadcast, 2-way max (free).
#define TM 256
#define BK 16
#define LDSA 260  // 256+4 dwords: 1040 B row stride, 16B-aligned
#define LDSB 68   // 64+4 dwords: 272 B row stride, 16B-aligned

template <int SK>
__global__ __launch_bounds__(256, 2) void gemm_partial_kernel(
    const float* __restrict__ x, const float* __restrict__ w1,
    float* __restrict__ hp) {
  constexpr int KS = DM / SK;
  constexpr int NCH = KS / BK;
  __shared__ float As[2][BK * LDSA];  // 33.3 KB
  __shared__ float Ws[2][BK * LDSB];  // 8.7 KB
  const int tid = threadIdx.x;
  const int kz = blockIdx.x % SK;
  const int mb = blockIdx.x / SK;
  const int row0 = mb * TM;
  const int kbase = kz * KS;
  const int m0 = (tid >> 3) * 8;  // 0..248
  const int n0 = (tid & 7) * 8;   // 0..56
  const int tS = tid >> 2;        // 0..63: token/expert row group for staging
  const int kS = (tid & 3) * 4;   // 0,4,8,12: k offset within chunk

  float acc[8][8];
#pragma unroll
  for (int i = 0; i < 8; ++i)
#pragma unroll
    for (int j = 0; j < 8; ++j) acc[i][j] = 0.f;

  // staging registers: A = 4 float4 (rows tS+64*it), B = 1 float4 (row tS)
  float4 ra[4], rw;
  const float* xptr = &x[(size_t)(row0 + tS) * DM + kS];
  const float* wptr = &w1[(size_t)tS * DM + kS];

#define LOAD_TILE(KC)                                                     \
  do {                                                                    \
    _Pragma("unroll") for (int it = 0; it < 4; ++it) ra[it] =             \
        *reinterpret_cast<const float4*>(xptr + (size_t)64 * it * DM +    \
                                         (KC));                           \
    rw = *reinterpret_cast<const float4*>(wptr + (KC));                   \
  } while (0)

#define STORE_TILE(B)                                                     \
  do {                                                                    \
    _Pragma("unroll") for (int it = 0; it < 4; ++it) {                    \
      const int t = tS + 64 * it;                                         \
      As[B][(kS + 0) * LDSA + t] = ra[it].x;                              \
      As[B][(kS + 1) * LDSA + t] = ra[it].y;                              \
      As[B][(kS + 2) * LDSA + t] = ra[it].z;                              \
      As[B][(kS + 3) * LDSA + t] = ra[it].w;                              \
    }                                                                     \
    Ws[B][(kS + 0) * LDSB + tS] = rw.x;                                   \
    Ws[B][(kS + 1) * LDSB + tS] = rw.y;                                   \
    Ws[B][(kS + 2) * LDSB + tS] = rw.z;                                   \
    Ws[B][(kS + 3) * LDSB + tS] = rw.w;                                   \
  } while (0)

  // prologue: tile0 -> buf0, tile1 -> regs
  LOAD_TILE(kbase);
  STORE_TILE(0);
  if (NCH > 1) LOAD_TILE(kbase + BK);
  __syncthreads();

  for (int i = 0; i < NCH; ++i) {
    const int cur = i & 1;
    // phase: issue stores for tile i+1 and loads for tile i+2 first,
    // then compute tile i -- LDS writes + VMEM hide under FMAs.
    if (i + 1 < NCH) STORE_TILE(cur ^ 1);
    if (i + 2 < NCH) LOAD_TILE(kbase + (i + 2) * BK);
#pragma unroll
    for (int k = 0; k < BK; ++k) {
      const float4 a0 =
          *reinterpret_cast<const float4*>(&As[cur][k * LDSA + m0]);
      const float4 a1 =
          *reinterpret_cast<const float4*>(&As[cur][k * LDSA + m0 + 4]);
      const float4 b0 =
          *reinterpret_cast<const float4*>(&Ws[cur][k * LDSB + n0]);
      const float4 b1 =
          *reinterpret_cast<const float4*>(&Ws[cur][k * LDSB + n0 + 4]);
      const float a[8] = {a0.x, a0.y, a0.z, a0.w, a1.x, a1.y, a1.z, a1.w};
      const float b[8] = {b0.x, b0.y, b0.z, b0.w, b1.x, b1.y, b1.z, b1.w};
#pragma unroll
      for (int ii = 0; ii < 8; ++ii)
#pragma unroll
        for (int jj = 0; jj < 8; ++jj)
          acc[ii][jj] = fmaf(a[ii], b[jj], acc[ii][jj]);
    }
    __syncthreads();
  }
#undef LOAD_TILE
#undef STORE_TILE

  float* dst = hp + (size_t)kz * TOKENS * NE;
#pragma unroll
  for (int i = 0; i < 8; ++i) {
    const size_t o = (size_t)(row0 + m0 + i) * NE;
    *reinterpret_cast<float4*>(&dst[o + n0]) =
        make_float4(acc[i][0], acc[i][1], acc[i][2], acc[i][3]);
    *reinterpret_cast<float4*>(&dst[o + n0 + 4]) =
        make_float4(acc[i][4], acc[i][5], acc[i][6], acc[i][7]);
  }
}

// ================= Kernel B: gate =================
template <int SK>
__global__ __launch_bounds__(256) void gate_kernel(
    const float* __restrict__ hp, const float* __restrict__ w2,
    const float* __restrict__ noise, float* __restrict__ out_idx,
    float* __restrict__ out_score, float* __restrict__ imp_part,
    float* __restrict__ load_part) {
  __shared__ float hs[TG * 65];
  __shared__ float w2s[NE * 65];
  __shared__ float ls[TG * 66];
  __shared__ float csum[2 * NE];
  __shared__ int hist[NE];
  const int tid = threadIdx.x;
  const int t0 = blockIdx.x * TG;
  if (tid < NE) hist[tid] = 0;

  // stage hs = tanh(sum of SK partials): 64*16 float4s, 4/thread
#pragma unroll
  for (int it = 0; it < 4; ++it) {
    const int f = tid + 256 * it;
    const int c = f & 15;
    const int t = f >> 4;
    const size_t g = (size_t)(t0 + t) * NE + c * 4;
    float4 p = *reinterpret_cast<const float4*>(&hp[g]);
#pragma unroll
    for (int s = 1; s < SK; ++s) {
      const float4 q =
          *reinterpret_cast<const float4*>(&hp[(size_t)s * TOKENS * NE + g]);
      p.x += q.x; p.y += q.y; p.z += q.z; p.w += q.w;
    }
    float* d = &hs[t * 65 + c * 4];
    d[0] = tanhf(p.x);
    d[1] = tanhf(p.y);
    d[2] = tanhf(p.z);
    d[3] = tanhf(p.w);
  }
  // stage w2 [64x64]
#pragma unroll
  for (int it = 0; it < 4; ++it) {
    const int f = tid + 256 * it;
    const int c = f & 15;
    const int r = f >> 4;
    const float4 v =
        *reinterpret_cast<const float4*>(&w2[(size_t)r * NE + c * 4]);
    float* d = &w2s[r * 65 + c * 4];
    d[0] = v.x; d[1] = v.y; d[2] = v.z; d[3] = v.w;
  }
  __syncthreads();

  // phase 1: logits = hs @ w2s^T, 4x4 per thread
  {
    const int m0 = (tid >> 4) * 4;
    const int n0 = (tid & 15) * 4;
    float acc[4][4];
#pragma unroll
    for (int i = 0; i < 4; ++i)
#pragma unroll
      for (int j = 0; j < 4; ++j) acc[i][j] = 0.f;
#pragma unroll 8
    for (int k = 0; k < NE; ++k) {
      float a[4], b[4];
#pragma unroll
      for (int i = 0; i < 4; ++i) a[i] = hs[(m0 + i) * 65 + k];
#pragma unroll
      for (int j = 0; j < 4; ++j) b[j] = w2s[(n0 + j) * 65 + k];
#pragma unroll
      for (int i = 0; i < 4; ++i)
#pragma unroll
        for (int j = 0; j < 4; ++j) acc[i][j] = fmaf(a[i], b[j], acc[i][j]);
    }
#pragma unroll
    for (int i = 0; i < 4; ++i)
#pragma unroll
      for (int j = 0; j < 4; ++j) ls[(m0 + i) * 66 + n0 + j] = acc[i][j];
  }
  __syncthreads();

  // phase 2: per-token softmax + gumbel argmax (1 wave)
  if (tid < TG) {
    const int t = tid;
    float mx = -INFINITY, best = -INFINITY;
    int bi = 0;
    for (int e = 0; e < NE; ++e) {
      const float l = ls[t * 66 + e];
      mx = fmaxf(mx, l);
      const float g = l + noise[(size_t)(t0 + t) * NE + e];
      if (g > best) { best = g; bi = e; }
    }
    float s = 0.f;
    for (int e = 0; e < NE; ++e) {
      const float ex = expf(ls[t * 66 + e] - mx);
      s += ex;
      ls[t * 66 + e] = ex;
    }
    const float inv = 1.f / s;
    for (int e = 0; e < NE; ++e) ls[t * 66 + e] *= inv;
    out_idx[t0 + t] = (float)bi;
    out_score[t0 + t] = best;
    atomicAdd(&hist[bi], 1);
  }
  __syncthreads();

  // phase 3: column sums of scores
  if (tid < 128) {
    const int e = tid & 63;
    const int half = tid >> 6;
    float s = 0.f;
    for (int r = half * 32; r < half * 32 + 32; ++r) s += ls[r * 66 + e];
    csum[half * NE + e] = s;
  }
  __syncthreads();
  if (tid < NE) {
    imp_part[(size_t)blockIdx.x * NE + tid] = csum[tid] + csum[NE + tid];
    load_part[(size_t)blockIdx.x * NE + tid] = (float)hist[tid];
  }
}

// ================= Kernel C: finalize =================
__global__ void finalize_kernel(const float* __restrict__ imp_part,
                                const float* __restrict__ load_part,
                                float* __restrict__ out) {
  const int e = threadIdx.x;  // 64 threads, 1 wave
  float imp = 0.f, ld = 0.f;
  for (int b = 0; b < GBLOCKS; ++b) {
    imp += imp_part[(size_t)b * NE + e];
    ld += load_part[(size_t)b * NE + e];
  }
  const float imp_mean = imp / (float)TOKENS;
  const float load_mean = ld / (float)TOKENS;
  out[2 * TOKENS + 1 + e] = load_mean;
  out[2 * TOKENS + 1 + NE + e] = imp_mean;
  float prod = imp_mean * load_mean;
#pragma unroll
  for (int off = 32; off > 0; off >>= 1) prod += __shfl_down(prod, off);
  if (e == 0) out[2 * TOKENS] = (float)NE * prod * BALW;
}

// ================= launch =================
extern "C" void kernel_launch(void* const* d_in, const int* in_sizes, int n_in,
                              void* d_out, int out_size, void* d_ws,
                              size_t ws_size, hipStream_t stream) {
  const float* x = (const float*)d_in[0];
  const float* w1 = (const float*)d_in[1];
  const float* w2 = (const float*)d_in[2];
  const float* noise = (const float*)d_in[3];
  float* out = (float*)d_out;

  const size_t part_elems = (size_t)2 * GBLOCKS * NE;
  const size_t need4 =
      ((size_t)4 * TOKENS * NE + part_elems) * sizeof(float);  // ~33.8 MB

  if (ws_size == 0 || ws_size >= need4) {
    // primary: SPLITK=4 -> 512 blocks, 2 blocks/CU
    float* hp = (float*)d_ws;
    float* imp_part = hp + (size_t)4 * TOKENS * NE;
    float* load_part = imp_part + (size_t)GBLOCKS * NE;
    hipLaunchKernelGGL((gemm_partial_kernel<4>), dim3((TOKENS / TM) * 4),
                       dim3(256), 0, stream, x, w1, hp);
    hipLaunchKernelGGL((gate_kernel<4>), dim3(GBLOCKS), dim3(256), 0, stream,
                       hp, w2, noise, out, out + TOKENS, imp_part, load_part);
    hipLaunchKernelGGL(finalize_kernel, dim3(1), dim3(64), 0, stream, imp_part,
                       load_part, out);
  } else {
    // fallback: SPLITK=2 (smaller workspace), same pipelined kernel
    float* hp = (float*)d_ws;
    float* imp_part = hp + (size_t)2 * TOKENS * NE;
    float* load_part = imp_part + (size_t)GBLOCKS * NE;
    hipLaunchKernelGGL((gemm_partial_kernel<2>), dim3((TOKENS / TM) * 2),
                       dim3(256), 0, stream, x, w1, hp);
    hipLaunchKernelGGL((gate_kernel<2>), dim3(GBLOCKS), dim3(256), 0, stream,
                       hp, w2, noise, out, out + TOKENS, imp_part, load_part);
    hipLaunchKernelGGL(finalize_kernel, dim3(1), dim3(64), 0, stream, imp_part,
                       load_part, out);
  }
}

// Round 3
// 265.585 us; speedup vs baseline: 1.2135x; 1.2135x over previous
//
#include <hip/hip_runtime.h>
#include <math.h>

// Problem constants
#define TOKENS 32768
#define DM 4096
#define NE 64
#define BALW 0.1f

#define TG 64
#define GBLOCKS (TOKENS / TG)  // 512

// ================= Kernel A: 128x64 tile, 4x8/thread, BK=32, 4 blocks/CU ====
// grid = (TOKENS/TM) * SK = 256*4 = 1024 blocks -> 4 blocks/CU, 16 waves/CU.
// R1's proven 2-barrier schedule; the barrier/store bubbles of one block are
// covered by the other 3 blocks' compute (independent barrier domains).
// As k-major [32][132] (16.9 KB), Ws k-major [32][68] (8.7 KB) = 25.6 KB.
// A-frag read: 1x ds_read_b128, 8 distinct bank-quads, conflict-free.
// B-frag read: 2x ds_read_b128, 2-way broadcast (free).
// Staged writes: bank = (16*(tid&3)+4c+rS)%32 -> exactly 2-way (free).
#define TM 128
#define BK 32
#define LDSA 132  // 128+4 dwords: 528 B row stride, 16B-aligned
#define LDSB 68   // 64+4 dwords: 272 B row stride, 16B-aligned

template <int SK>
__global__ __launch_bounds__(256, 4) void gemm_partial_kernel(
    const float* __restrict__ x, const float* __restrict__ w1,
    float* __restrict__ hp) {
  constexpr int KS = DM / SK;
  __shared__ float As[BK * LDSA];
  __shared__ float Ws[BK * LDSB];
  const int tid = threadIdx.x;
  const int kz = blockIdx.x % SK;
  const int mb = blockIdx.x / SK;
  const int row0 = mb * TM;
  const int kbase = kz * KS;
  const int m0 = (tid >> 3) * 4;  // 0..124
  const int n0 = (tid & 7) * 8;   // 0..56
  const int rS = tid >> 2;        // 0..63: staging row
  const int kS = (tid & 3) * 4;   // 0,4,8,12: staging k offset (+16 half)

  float acc[4][8];
#pragma unroll
  for (int i = 0; i < 4; ++i)
#pragma unroll
    for (int j = 0; j < 8; ++j) acc[i][j] = 0.f;

  // staging regs: A rows {rS, rS+64} x k-chunks {kS, kS+16}; W row rS x both
  float4 ra[4], rw[2];
  const float* xp = &x[(size_t)(row0 + rS) * DM + kS];
  const float* wp = &w1[(size_t)rS * DM + kS];

#define LOAD_TILE(KC)                                                   \
  do {                                                                  \
    ra[0] = *reinterpret_cast<const float4*>(xp + (KC));                \
    ra[1] = *reinterpret_cast<const float4*>(xp + (KC) + 16);           \
    ra[2] = *reinterpret_cast<const float4*>(xp + (size_t)64 * DM + (KC));\
    ra[3] = *reinterpret_cast<const float4*>(xp + (size_t)64 * DM + (KC) + 16);\
    rw[0] = *reinterpret_cast<const float4*>(wp + (KC));                \
    rw[1] = *reinterpret_cast<const float4*>(wp + (KC) + 16);           \
  } while (0)

#define ST4(arr, stride, krow, col, v)                                  \
  do {                                                                  \
    arr[((krow) + 0) * (stride) + (col)] = (v).x;                       \
    arr[((krow) + 1) * (stride) + (col)] = (v).y;                       \
    arr[((krow) + 2) * (stride) + (col)] = (v).z;                       \
    arr[((krow) + 3) * (stride) + (col)] = (v).w;                       \
  } while (0)

#define STORE_TILE()                                                    \
  do {                                                                  \
    ST4(As, LDSA, kS, rS, ra[0]);                                       \
    ST4(As, LDSA, kS + 16, rS, ra[1]);                                  \
    ST4(As, LDSA, kS, rS + 64, ra[2]);                                  \
    ST4(As, LDSA, kS + 16, rS + 64, ra[3]);                             \
    ST4(Ws, LDSB, kS, rS, rw[0]);                                       \
    ST4(Ws, LDSB, kS + 16, rS, rw[1]);                                  \
  } while (0)

  LOAD_TILE(kbase);

  for (int kc = kbase; kc < kbase + KS; kc += BK) {
    __syncthreads();  // everyone done reading LDS from previous chunk
    STORE_TILE();
    __syncthreads();
    if (kc + BK < kbase + KS) LOAD_TILE(kc + BK);  // hide under compute
#pragma unroll 8
    for (int k = 0; k < BK; ++k) {
      const float4 a0 = *reinterpret_cast<const float4*>(&As[k * LDSA + m0]);
      const float4 b0 = *reinterpret_cast<const float4*>(&Ws[k * LDSB + n0]);
      const float4 b1 =
          *reinterpret_cast<const float4*>(&Ws[k * LDSB + n0 + 4]);
      const float a[4] = {a0.x, a0.y, a0.z, a0.w};
      const float b[8] = {b0.x, b0.y, b0.z, b0.w, b1.x, b1.y, b1.z, b1.w};
#pragma unroll
      for (int i = 0; i < 4; ++i)
#pragma unroll
        for (int j = 0; j < 8; ++j) acc[i][j] = fmaf(a[i], b[j], acc[i][j]);
    }
  }
#undef LOAD_TILE
#undef ST4
#undef STORE_TILE

  float* dst = hp + (size_t)kz * TOKENS * NE;
#pragma unroll
  for (int i = 0; i < 4; ++i) {
    const size_t o = (size_t)(row0 + m0 + i) * NE;
    *reinterpret_cast<float4*>(&dst[o + n0]) =
        make_float4(acc[i][0], acc[i][1], acc[i][2], acc[i][3]);
    *reinterpret_cast<float4*>(&dst[o + n0 + 4]) =
        make_float4(acc[i][4], acc[i][5], acc[i][6], acc[i][7]);
  }
}

// ================= Kernel B: gate =================
template <int SK>
__global__ __launch_bounds__(256) void gate_kernel(
    const float* __restrict__ hp, const float* __restrict__ w2,
    const float* __restrict__ noise, float* __restrict__ out_idx,
    float* __restrict__ out_score, float* __restrict__ imp_part,
    float* __restrict__ load_part) {
  __shared__ float hs[TG * 65];
  __shared__ float w2s[NE * 65];
  __shared__ float ls[TG * 66];
  __shared__ float csum[2 * NE];
  __shared__ int hist[NE];
  const int tid = threadIdx.x;
  const int t0 = blockIdx.x * TG;
  if (tid < NE) hist[tid] = 0;

  // stage hs = tanh(sum of SK partials): 64*16 float4s, 4/thread
#pragma unroll
  for (int it = 0; it < 4; ++it) {
    const int f = tid + 256 * it;
    const int c = f & 15;
    const int t = f >> 4;
    const size_t g = (size_t)(t0 + t) * NE + c * 4;
    float4 p = *reinterpret_cast<const float4*>(&hp[g]);
#pragma unroll
    for (int s = 1; s < SK; ++s) {
      const float4 q =
          *reinterpret_cast<const float4*>(&hp[(size_t)s * TOKENS * NE + g]);
      p.x += q.x; p.y += q.y; p.z += q.z; p.w += q.w;
    }
    float* d = &hs[t * 65 + c * 4];
    d[0] = tanhf(p.x);
    d[1] = tanhf(p.y);
    d[2] = tanhf(p.z);
    d[3] = tanhf(p.w);
  }
  // stage w2 [64x64]
#pragma unroll
  for (int it = 0; it < 4; ++it) {
    const int f = tid + 256 * it;
    const int c = f & 15;
    const int r = f >> 4;
    const float4 v =
        *reinterpret_cast<const float4*>(&w2[(size_t)r * NE + c * 4]);
    float* d = &w2s[r * 65 + c * 4];
    d[0] = v.x; d[1] = v.y; d[2] = v.z; d[3] = v.w;
  }
  __syncthreads();

  // phase 1: logits = hs @ w2s^T, 4x4 per thread
  {
    const int m0 = (tid >> 4) * 4;
    const int n0 = (tid & 15) * 4;
    float acc[4][4];
#pragma unroll
    for (int i = 0; i < 4; ++i)
#pragma unroll
      for (int j = 0; j < 4; ++j) acc[i][j] = 0.f;
#pragma unroll 8
    for (int k = 0; k < NE; ++k) {
      float a[4], b[4];
#pragma unroll
      for (int i = 0; i < 4; ++i) a[i] = hs[(m0 + i) * 65 + k];
#pragma unroll
      for (int j = 0; j < 4; ++j) b[j] = w2s[(n0 + j) * 65 + k];
#pragma unroll
      for (int i = 0; i < 4; ++i)
#pragma unroll
        for (int j = 0; j < 4; ++j) acc[i][j] = fmaf(a[i], b[j], acc[i][j]);
    }
#pragma unroll
    for (int i = 0; i < 4; ++i)
#pragma unroll
      for (int j = 0; j < 4; ++j) ls[(m0 + i) * 66 + n0 + j] = acc[i][j];
  }
  __syncthreads();

  // phase 2: per-token softmax + gumbel argmax (1 wave)
  if (tid < TG) {
    const int t = tid;
    float mx = -INFINITY, best = -INFINITY;
    int bi = 0;
    for (int e = 0; e < NE; ++e) {
      const float l = ls[t * 66 + e];
      mx = fmaxf(mx, l);
      const float g = l + noise[(size_t)(t0 + t) * NE + e];
      if (g > best) { best = g; bi = e; }
    }
    float s = 0.f;
    for (int e = 0; e < NE; ++e) {
      const float ex = expf(ls[t * 66 + e] - mx);
      s += ex;
      ls[t * 66 + e] = ex;
    }
    const float inv = 1.f / s;
    for (int e = 0; e < NE; ++e) ls[t * 66 + e] *= inv;
    out_idx[t0 + t] = (float)bi;
    out_score[t0 + t] = best;
    atomicAdd(&hist[bi], 1);
  }
  __syncthreads();

  // phase 3: column sums of scores
  if (tid < 128) {
    const int e = tid & 63;
    const int half = tid >> 6;
    float s = 0.f;
    for (int r = half * 32; r < half * 32 + 32; ++r) s += ls[r * 66 + e];
    csum[half * NE + e] = s;
  }
  __syncthreads();
  if (tid < NE) {
    imp_part[(size_t)blockIdx.x * NE + tid] = csum[tid] + csum[NE + tid];
    load_part[(size_t)blockIdx.x * NE + tid] = (float)hist[tid];
  }
}

// ================= Kernel C: finalize =================
__global__ void finalize_kernel(const float* __restrict__ imp_part,
                                const float* __restrict__ load_part,
                                float* __restrict__ out) {
  const int e = threadIdx.x;  // 64 threads, 1 wave
  float imp = 0.f, ld = 0.f;
  for (int b = 0; b < GBLOCKS; ++b) {
    imp += imp_part[(size_t)b * NE + e];
    ld += load_part[(size_t)b * NE + e];
  }
  const float imp_mean = imp / (float)TOKENS;
  const float load_mean = ld / (float)TOKENS;
  out[2 * TOKENS + 1 + e] = load_mean;
  out[2 * TOKENS + 1 + NE + e] = imp_mean;
  float prod = imp_mean * load_mean;
#pragma unroll
  for (int off = 32; off > 0; off >>= 1) prod += __shfl_down(prod, off);
  if (e == 0) out[2 * TOKENS] = (float)NE * prod * BALW;
}

// ================= launch =================
extern "C" void kernel_launch(void* const* d_in, const int* in_sizes, int n_in,
                              void* d_out, int out_size, void* d_ws,
                              size_t ws_size, hipStream_t stream) {
  const float* x = (const float*)d_in[0];
  const float* w1 = (const float*)d_in[1];
  const float* w2 = (const float*)d_in[2];
  const float* noise = (const float*)d_in[3];
  float* out = (float*)d_out;

  const size_t part_elems = (size_t)2 * GBLOCKS * NE;
  const size_t need4 =
      ((size_t)4 * TOKENS * NE + part_elems) * sizeof(float);  // ~33.8 MB

  if (ws_size == 0 || ws_size >= need4) {
    // primary: SPLITK=4 -> 1024 blocks, 4 blocks/CU
    float* hp = (float*)d_ws;
    float* imp_part = hp + (size_t)4 * TOKENS * NE;
    float* load_part = imp_part + (size_t)GBLOCKS * NE;
    hipLaunchKernelGGL((gemm_partial_kernel<4>), dim3((TOKENS / TM) * 4),
                       dim3(256), 0, stream, x, w1, hp);
    hipLaunchKernelGGL((gate_kernel<4>), dim3(GBLOCKS), dim3(256), 0, stream,
                       hp, w2, noise, out, out + TOKENS, imp_part, load_part);
    hipLaunchKernelGGL(finalize_kernel, dim3(1), dim3(64), 0, stream, imp_part,
                       load_part, out);
  } else {
    // fallback: SPLITK=2 (smaller workspace), same kernel, 512 blocks
    float* hp = (float*)d_ws;
    float* imp_part = hp + (size_t)2 * TOKENS * NE;
    float* load_part = imp_part + (size_t)GBLOCKS * NE;
    hipLaunchKernelGGL((gemm_partial_kernel<2>), dim3((TOKENS / TM) * 2),
                       dim3(256), 0, stream, x, w1, hp);
    hipLaunchKernelGGL((gate_kernel<2>), dim3(GBLOCKS), dim3(256), 0, stream,
                       hp, w2, noise, out, out + TOKENS, imp_part, load_part);
    hipLaunchKernelGGL(finalize_kernel, dim3(1), dim3(64), 0, stream, imp_part,
                       load_part, out);
  }
}

// Round 4
// 218.090 us; speedup vs baseline: 1.4777x; 1.2178x over previous
//
#include <hip/hip_runtime.h>
#include <math.h>

// Problem constants
#define TOKENS 32768
#define DM 4096
#define NE 64
#define BALW 0.1f

#define TG 64
#define GBLOCKS (TOKENS / TG)  // 512

typedef __attribute__((ext_vector_type(8))) short short8;   // 8 bf16 = 4 VGPR
typedef __attribute__((ext_vector_type(4))) float f32x4;    // MFMA acc

typedef unsigned short us;

// ---- exact fp32 -> 3x bf16 split helpers (RNE) ----
__device__ inline us bf16r(float f) {
  const unsigned u = __float_as_uint(f);
  return (us)((u + 0x7FFFu + ((u >> 16) & 1u)) >> 16);
}
__device__ inline float bf16f(us s) {
  return __uint_as_float(((unsigned)s) << 16);
}
__device__ inline void split8(const float4 v0, const float4 v1, short8& H,
                              short8& M, short8& L) {
  float v[8] = {v0.x, v0.y, v0.z, v0.w, v1.x, v1.y, v1.z, v1.w};
#pragma unroll
  for (int j = 0; j < 8; ++j) {
    const us hs = bf16r(v[j]);
    const float r1 = v[j] - bf16f(hs);  // exact (Sterbenz)
    const us ms = bf16r(r1);
    const float r2 = r1 - bf16f(ms);    // exact
    const us ls = bf16r(r2);
    H[j] = (short)hs; M[j] = (short)ms; L[j] = (short)ls;
  }
}

#define MFMA(a, b, c) __builtin_amdgcn_mfma_f32_16x16x32_bf16(a, b, c, 0, 0, 0)

// ================= Kernel P: pre-split w1 into MFMA B-frag order =============
// bws layout: for k-chunk kc (32 k), n-subtile ns (16 experts), plane p:
// block of 512 shorts at ((kc*4+ns)*3+p)*512; lane l holds 8 bf16 at l*8:
// w1_plane_p[n=16ns+(l&15)][k=32kc+8*(l>>4)+j]  (MFMA B-frag layout).
__global__ void prep_w1_kernel(const float* __restrict__ w1,
                               us* __restrict__ bws) {
  const int kc = blockIdx.x;       // 0..127
  const int tid = threadIdx.x;     // 256
  const int ns = tid >> 6;
  const int l = tid & 63;
  const int r = l & 15, g = l >> 4;
  const int n = 16 * ns + r;
  const int kb = 32 * kc + 8 * g;
  const float* src = &w1[(size_t)n * DM + kb];
  const float4 v0 = *reinterpret_cast<const float4*>(src);
  const float4 v1 = *reinterpret_cast<const float4*>(src + 4);
  short8 H, M, L;
  split8(v0, v1, H, M, L);
  us* dst = bws + ((size_t)(kc * 4 + ns) * 3) * 512 + l * 8;
  *reinterpret_cast<short8*>(dst) = H;
  *reinterpret_cast<short8*>(dst + 512) = M;
  *reinterpret_cast<short8*>(dst + 1024) = L;
}

// ================= Kernel A (primary): MFMA bf16x3 GEMM ======================
// grid = (TOKENS/128)*SK = 256*4 = 1024 blocks, 4 waves each. Wave tile:
// 32 tokens x 64 experts. No LDS, no barriers: A fp32 from global -> split in
// regs; B from pre-split bws (L1/L2-resident, coalesced 1KB wave loads).
// 8 product terms (hh,hm,mh,hl,mm,lh,ml,lm) -> error ~ fp32 rounding.
// HBM-bound: x read once = 512 MB.
#define TMM 128

template <int SK>
__global__ __launch_bounds__(256, 3) void gemm_mfma_kernel(
    const float* __restrict__ x, const us* __restrict__ bws,
    float* __restrict__ hp) {
  constexpr int KS = DM / SK;
  constexpr int NIT = KS / 32;
  const int tid = threadIdx.x;
  const int kz = blockIdx.x % SK;
  const int mb = blockIdx.x / SK;
  const int w = tid >> 6;
  const int l = tid & 63;
  const int r = l & 15, g = l >> 4;
  const int row0 = mb * TMM + w * 32;
  const int kb0 = kz * KS;

  f32x4 acc[2][4];
#pragma unroll
  for (int i = 0; i < 2; ++i)
#pragma unroll
    for (int j = 0; j < 4; ++j) acc[i][j] = (f32x4)(0.f);

  const float* xA0 = &x[(size_t)(row0 + r) * DM + kb0 + 8 * g];
  const float* xA1 = xA0 + (size_t)16 * DM;
  const us* bb = bws + (size_t)(kb0 / 32) * 12 * 512 + l * 8;

  for (int it = 0; it < NIT; ++it) {
    const int koff = it * 32;
    // A raw loads: per ms-subtile, lane reads 8 contiguous fp32 (32B);
    // the 4 lane-groups of a row tile a contiguous 128B line.
    const float4 a00 = *reinterpret_cast<const float4*>(xA0 + koff);
    const float4 a01 = *reinterpret_cast<const float4*>(xA0 + koff + 4);
    const float4 a10 = *reinterpret_cast<const float4*>(xA1 + koff);
    const float4 a11 = *reinterpret_cast<const float4*>(xA1 + koff + 4);
    // B frags: 12 coalesced 1KB wave loads (L1-resident across waves)
    const us* bt = bb + (size_t)it * 12 * 512;
    short8 bf[4][3];
#pragma unroll
    for (int ns = 0; ns < 4; ++ns)
#pragma unroll
      for (int p = 0; p < 3; ++p)
        bf[ns][p] =
            *reinterpret_cast<const short8*>(bt + (ns * 3 + p) * 512);

    short8 ah, am, al;
    split8(a00, a01, ah, am, al);
#pragma unroll
    for (int ns = 0; ns < 4; ++ns) {
      f32x4 c = acc[0][ns];
      c = MFMA(ah, bf[ns][0], c);
      c = MFMA(ah, bf[ns][1], c);
      c = MFMA(am, bf[ns][0], c);
      c = MFMA(ah, bf[ns][2], c);
      c = MFMA(am, bf[ns][1], c);
      c = MFMA(al, bf[ns][0], c);
      c = MFMA(am, bf[ns][2], c);
      c = MFMA(al, bf[ns][1], c);
      acc[0][ns] = c;
    }
    split8(a10, a11, ah, am, al);
#pragma unroll
    for (int ns = 0; ns < 4; ++ns) {
      f32x4 c = acc[1][ns];
      c = MFMA(ah, bf[ns][0], c);
      c = MFMA(ah, bf[ns][1], c);
      c = MFMA(am, bf[ns][0], c);
      c = MFMA(ah, bf[ns][2], c);
      c = MFMA(am, bf[ns][1], c);
      c = MFMA(al, bf[ns][0], c);
      c = MFMA(am, bf[ns][2], c);
      c = MFMA(al, bf[ns][1], c);
      acc[1][ns] = c;
    }
  }

  // C/D layout: col = lane&15, row = 4*(lane>>4) + reg
  float* dst = hp + (size_t)kz * TOKENS * NE;
#pragma unroll
  for (int ms = 0; ms < 2; ++ms)
#pragma unroll
    for (int ns = 0; ns < 4; ++ns)
#pragma unroll
      for (int q = 0; q < 4; ++q)
        dst[(size_t)(row0 + 16 * ms + 4 * g + q) * NE + 16 * ns + r] =
            acc[ms][ns][q];
}

// ================= Kernel A (fallback, proven fp32): 128x64, 4x8/thread =====
#define TM 128
#define BK 32
#define LDSA 132
#define LDSB 68

template <int SK>
__global__ __launch_bounds__(256, 4) void gemm_fp32_kernel(
    const float* __restrict__ x, const float* __restrict__ w1,
    float* __restrict__ hp) {
  constexpr int KS = DM / SK;
  __shared__ float As[BK * LDSA];
  __shared__ float Ws[BK * LDSB];
  const int tid = threadIdx.x;
  const int kz = blockIdx.x % SK;
  const int mb = blockIdx.x / SK;
  const int row0 = mb * TM;
  const int kbase = kz * KS;
  const int m0 = (tid >> 3) * 4;
  const int n0 = (tid & 7) * 8;
  const int rS = tid >> 2;
  const int kS = (tid & 3) * 4;

  float acc[4][8];
#pragma unroll
  for (int i = 0; i < 4; ++i)
#pragma unroll
    for (int j = 0; j < 8; ++j) acc[i][j] = 0.f;

  float4 ra[4], rw[2];
  const float* xp = &x[(size_t)(row0 + rS) * DM + kS];
  const float* wp = &w1[(size_t)rS * DM + kS];

#define LOAD_TILE(KC)                                                   \
  do {                                                                  \
    ra[0] = *reinterpret_cast<const float4*>(xp + (KC));                \
    ra[1] = *reinterpret_cast<const float4*>(xp + (KC) + 16);           \
    ra[2] = *reinterpret_cast<const float4*>(xp + (size_t)64 * DM + (KC));\
    ra[3] = *reinterpret_cast<const float4*>(xp + (size_t)64 * DM + (KC) + 16);\
    rw[0] = *reinterpret_cast<const float4*>(wp + (KC));                \
    rw[1] = *reinterpret_cast<const float4*>(wp + (KC) + 16);           \
  } while (0)

#define ST4(arr, stride, krow, col, v)                                  \
  do {                                                                  \
    arr[((krow) + 0) * (stride) + (col)] = (v).x;                       \
    arr[((krow) + 1) * (stride) + (col)] = (v).y;                       \
    arr[((krow) + 2) * (stride) + (col)] = (v).z;                       \
    arr[((krow) + 3) * (stride) + (col)] = (v).w;                       \
  } while (0)

#define STORE_TILE()                                                    \
  do {                                                                  \
    ST4(As, LDSA, kS, rS, ra[0]);                                       \
    ST4(As, LDSA, kS + 16, rS, ra[1]);                                  \
    ST4(As, LDSA, kS, rS + 64, ra[2]);                                  \
    ST4(As, LDSA, kS + 16, rS + 64, ra[3]);                             \
    ST4(Ws, LDSB, kS, rS, rw[0]);                                       \
    ST4(Ws, LDSB, kS + 16, rS, rw[1]);                                  \
  } while (0)

  LOAD_TILE(kbase);

  for (int kc = kbase; kc < kbase + KS; kc += BK) {
    __syncthreads();
    STORE_TILE();
    __syncthreads();
    if (kc + BK < kbase + KS) LOAD_TILE(kc + BK);
#pragma unroll 8
    for (int k = 0; k < BK; ++k) {
      const float4 a0 = *reinterpret_cast<const float4*>(&As[k * LDSA + m0]);
      const float4 b0 = *reinterpret_cast<const float4*>(&Ws[k * LDSB + n0]);
      const float4 b1 =
          *reinterpret_cast<const float4*>(&Ws[k * LDSB + n0 + 4]);
      const float a[4] = {a0.x, a0.y, a0.z, a0.w};
      const float b[8] = {b0.x, b0.y, b0.z, b0.w, b1.x, b1.y, b1.z, b1.w};
#pragma unroll
      for (int i = 0; i < 4; ++i)
#pragma unroll
        for (int j = 0; j < 8; ++j) acc[i][j] = fmaf(a[i], b[j], acc[i][j]);
    }
  }
#undef LOAD_TILE
#undef ST4
#undef STORE_TILE

  float* dst = hp + (size_t)kz * TOKENS * NE;
#pragma unroll
  for (int i = 0; i < 4; ++i) {
    const size_t o = (size_t)(row0 + m0 + i) * NE;
    *reinterpret_cast<float4*>(&dst[o + n0]) =
        make_float4(acc[i][0], acc[i][1], acc[i][2], acc[i][3]);
    *reinterpret_cast<float4*>(&dst[o + n0 + 4]) =
        make_float4(acc[i][4], acc[i][5], acc[i][6], acc[i][7]);
  }
}

// ================= Kernel B: gate =================
template <int SK>
__global__ __launch_bounds__(256) void gate_kernel(
    const float* __restrict__ hp, const float* __restrict__ w2,
    const float* __restrict__ noise, float* __restrict__ out_idx,
    float* __restrict__ out_score, float* __restrict__ imp_part,
    float* __restrict__ load_part) {
  __shared__ float hs[TG * 65];
  __shared__ float w2s[NE * 65];
  __shared__ float ls[TG * 66];
  __shared__ float csum[2 * NE];
  __shared__ int hist[NE];
  const int tid = threadIdx.x;
  const int t0 = blockIdx.x * TG;
  if (tid < NE) hist[tid] = 0;

#pragma unroll
  for (int it = 0; it < 4; ++it) {
    const int f = tid + 256 * it;
    const int c = f & 15;
    const int t = f >> 4;
    const size_t g = (size_t)(t0 + t) * NE + c * 4;
    float4 p = *reinterpret_cast<const float4*>(&hp[g]);
#pragma unroll
    for (int s = 1; s < SK; ++s) {
      const float4 q =
          *reinterpret_cast<const float4*>(&hp[(size_t)s * TOKENS * NE + g]);
      p.x += q.x; p.y += q.y; p.z += q.z; p.w += q.w;
    }
    float* d = &hs[t * 65 + c * 4];
    d[0] = tanhf(p.x);
    d[1] = tanhf(p.y);
    d[2] = tanhf(p.z);
    d[3] = tanhf(p.w);
  }
#pragma unroll
  for (int it = 0; it < 4; ++it) {
    const int f = tid + 256 * it;
    const int c = f & 15;
    const int rr = f >> 4;
    const float4 v =
        *reinterpret_cast<const float4*>(&w2[(size_t)rr * NE + c * 4]);
    float* d = &w2s[rr * 65 + c * 4];
    d[0] = v.x; d[1] = v.y; d[2] = v.z; d[3] = v.w;
  }
  __syncthreads();

  {
    const int m0 = (tid >> 4) * 4;
    const int n0 = (tid & 15) * 4;
    float acc[4][4];
#pragma unroll
    for (int i = 0; i < 4; ++i)
#pragma unroll
      for (int j = 0; j < 4; ++j) acc[i][j] = 0.f;
#pragma unroll 8
    for (int k = 0; k < NE; ++k) {
      float a[4], b[4];
#pragma unroll
      for (int i = 0; i < 4; ++i) a[i] = hs[(m0 + i) * 65 + k];
#pragma unroll
      for (int j = 0; j < 4; ++j) b[j] = w2s[(n0 + j) * 65 + k];
#pragma unroll
      for (int i = 0; i < 4; ++i)
#pragma unroll
        for (int j = 0; j < 4; ++j) acc[i][j] = fmaf(a[i], b[j], acc[i][j]);
    }
#pragma unroll
    for (int i = 0; i < 4; ++i)
#pragma unroll
      for (int j = 0; j < 4; ++j) ls[(m0 + i) * 66 + n0 + j] = acc[i][j];
  }
  __syncthreads();

  if (tid < TG) {
    const int t = tid;
    float mx = -INFINITY, best = -INFINITY;
    int bi = 0;
    for (int e = 0; e < NE; ++e) {
      const float lv = ls[t * 66 + e];
      mx = fmaxf(mx, lv);
      const float gg = lv + noise[(size_t)(t0 + t) * NE + e];
      if (gg > best) { best = gg; bi = e; }
    }
    float s = 0.f;
    for (int e = 0; e < NE; ++e) {
      const float ex = expf(ls[t * 66 + e] - mx);
      s += ex;
      ls[t * 66 + e] = ex;
    }
    const float inv = 1.f / s;
    for (int e = 0; e < NE; ++e) ls[t * 66 + e] *= inv;
    out_idx[t0 + t] = (float)bi;
    out_score[t0 + t] = best;
    atomicAdd(&hist[bi], 1);
  }
  __syncthreads();

  if (tid < 128) {
    const int e = tid & 63;
    const int half = tid >> 6;
    float s = 0.f;
    for (int rr = half * 32; rr < half * 32 + 32; ++rr) s += ls[rr * 66 + e];
    csum[half * NE + e] = s;
  }
  __syncthreads();
  if (tid < NE) {
    imp_part[(size_t)blockIdx.x * NE + tid] = csum[tid] + csum[NE + tid];
    load_part[(size_t)blockIdx.x * NE + tid] = (float)hist[tid];
  }
}

// ================= Kernel C: finalize =================
__global__ void finalize_kernel(const float* __restrict__ imp_part,
                                const float* __restrict__ load_part,
                                float* __restrict__ out) {
  const int e = threadIdx.x;
  float imp = 0.f, ld = 0.f;
  for (int b = 0; b < GBLOCKS; ++b) {
    imp += imp_part[(size_t)b * NE + e];
    ld += load_part[(size_t)b * NE + e];
  }
  const float imp_mean = imp / (float)TOKENS;
  const float load_mean = ld / (float)TOKENS;
  out[2 * TOKENS + 1 + e] = load_mean;
  out[2 * TOKENS + 1 + NE + e] = imp_mean;
  float prod = imp_mean * load_mean;
#pragma unroll
  for (int off = 32; off > 0; off >>= 1) prod += __shfl_down(prod, off);
  if (e == 0) out[2 * TOKENS] = (float)NE * prod * BALW;
}

// ================= launch =================
extern "C" void kernel_launch(void* const* d_in, const int* in_sizes, int n_in,
                              void* d_out, int out_size, void* d_ws,
                              size_t ws_size, hipStream_t stream) {
  const float* x = (const float*)d_in[0];
  const float* w1 = (const float*)d_in[1];
  const float* w2 = (const float*)d_in[2];
  const float* noise = (const float*)d_in[3];
  float* out = (float*)d_out;

  const size_t bws_shorts = (size_t)128 * 4 * 3 * 512;  // 786432 (1.5 MB)
  const size_t part_elems = (size_t)2 * GBLOCKS * NE;
  const size_t need_mfma = bws_shorts * sizeof(us) +
                           ((size_t)4 * TOKENS * NE + part_elems) *
                               sizeof(float);  // ~35.4 MB
  const size_t need_fp32 =
      ((size_t)2 * TOKENS * NE + part_elems) * sizeof(float);  // ~17 MB

  if (ws_size == 0 || ws_size >= need_mfma) {
    us* bws = (us*)d_ws;
    float* hp = (float*)(bws + bws_shorts);
    float* imp_part = hp + (size_t)4 * TOKENS * NE;
    float* load_part = imp_part + (size_t)GBLOCKS * NE;
    hipLaunchKernelGGL(prep_w1_kernel, dim3(128), dim3(256), 0, stream, w1,
                       bws);
    hipLaunchKernelGGL((gemm_mfma_kernel<4>), dim3((TOKENS / TMM) * 4),
                       dim3(256), 0, stream, x, bws, hp);
    hipLaunchKernelGGL((gate_kernel<4>), dim3(GBLOCKS), dim3(256), 0, stream,
                       hp, w2, noise, out, out + TOKENS, imp_part, load_part);
    hipLaunchKernelGGL(finalize_kernel, dim3(1), dim3(64), 0, stream, imp_part,
                       load_part, out);
  } else if (ws_size >= need_fp32) {
    float* hp = (float*)d_ws;
    float* imp_part = hp + (size_t)2 * TOKENS * NE;
    float* load_part = imp_part + (size_t)GBLOCKS * NE;
    hipLaunchKernelGGL((gemm_fp32_kernel<2>), dim3((TOKENS / TM) * 2),
                       dim3(256), 0, stream, x, w1, hp);
    hipLaunchKernelGGL((gate_kernel<2>), dim3(GBLOCKS), dim3(256), 0, stream,
                       hp, w2, noise, out, out + TOKENS, imp_part, load_part);
    hipLaunchKernelGGL(finalize_kernel, dim3(1), dim3(64), 0, stream, imp_part,
                       load_part, out);
  }
}

// Round 5
// 205.778 us; speedup vs baseline: 1.5662x; 1.0598x over previous
//
#include <hip/hip_runtime.h>
#include <math.h>

// Problem constants
#define TOKENS 32768
#define DM 4096
#define NE 64
#define BALW 0.1f

#define TG 64
#define GBLOCKS (TOKENS / TG)  // 512

typedef __attribute__((ext_vector_type(8))) short short8;   // 8 bf16 = 4 VGPR
typedef __attribute__((ext_vector_type(4))) float f32x4;    // MFMA acc

typedef unsigned short us;

// ---- RNE fp32 -> 3x bf16 split (used in B-prep only; runs once) ----
__device__ inline us bf16r(float f) {
  const unsigned u = __float_as_uint(f);
  return (us)((u + 0x7FFFu + ((u >> 16) & 1u)) >> 16);
}
__device__ inline float bf16f(us s) {
  return __uint_as_float(((unsigned)s) << 16);
}
__device__ inline void split8(const float4 v0, const float4 v1, short8& H,
                              short8& M, short8& L) {
  float v[8] = {v0.x, v0.y, v0.z, v0.w, v1.x, v1.y, v1.z, v1.w};
#pragma unroll
  for (int j = 0; j < 8; ++j) {
    const us hs = bf16r(v[j]);
    const float r1 = v[j] - bf16f(hs);  // exact (Sterbenz)
    const us ms = bf16r(r1);
    const float r2 = r1 - bf16f(ms);    // exact
    const us ls = bf16r(r2);
    H[j] = (short)hs; M[j] = (short)ms; L[j] = (short)ls;
  }
}

// ---- truncation fp32 -> 3x bf16 split (hot path: 44 VALU per 8 elems) ----
// h = v & 0xFFFF0000 (trunc toward 0), r1 = v-h exact (Sterbenz), etc.
// Representation error <= 2^-21 |v| vs 2^-24 for RNE -- negligible here.
// Planes packed 2-at-a-time with v_perm_b32 (1 instr per dword per plane).
__device__ inline void split8t(const float4 v0, const float4 v1, short8& H,
                               short8& M, short8& L) {
  unsigned u[8], um[8], ul[8];
  const float v[8] = {v0.x, v0.y, v0.z, v0.w, v1.x, v1.y, v1.z, v1.w};
#pragma unroll
  for (int j = 0; j < 8; ++j) {
    u[j] = __float_as_uint(v[j]);
    const float r1 = v[j] - __uint_as_float(u[j] & 0xFFFF0000u);
    um[j] = __float_as_uint(r1);
    const float r2 = r1 - __uint_as_float(um[j] & 0xFFFF0000u);
    ul[j] = __float_as_uint(r2);
  }
  union Cvt { unsigned u4[4]; short8 s8; } h, m, l;
#pragma unroll
  for (int d = 0; d < 4; ++d) {
    // dword d = (hi16(elem 2d+1) << 16) | hi16(elem 2d)
    h.u4[d] = __builtin_amdgcn_perm(u[2 * d + 1], u[2 * d], 0x07060302u);
    m.u4[d] = __builtin_amdgcn_perm(um[2 * d + 1], um[2 * d], 0x07060302u);
    l.u4[d] = __builtin_amdgcn_perm(ul[2 * d + 1], ul[2 * d], 0x07060302u);
  }
  H = h.s8; M = m.s8; L = l.s8;
}

#define MFMA(a, b, c) __builtin_amdgcn_mfma_f32_16x16x32_bf16(a, b, c, 0, 0, 0)

// ================= Kernel P: pre-split w1 into MFMA B-frag order =============
// bws layout: for k-chunk kc (32 k), n-subtile ns (16 experts), plane p:
// block of 512 shorts at ((kc*4+ns)*3+p)*512; lane l holds 8 bf16 at l*8:
// w1_plane_p[n=16ns+(l&15)][k=32kc+8*(l>>4)+j]  (MFMA B-frag layout).
__global__ void prep_w1_kernel(const float* __restrict__ w1,
                               us* __restrict__ bws) {
  const int kc = blockIdx.x;       // 0..127
  const int tid = threadIdx.x;     // 256
  const int ns = tid >> 6;
  const int l = tid & 63;
  const int r = l & 15, g = l >> 4;
  const int n = 16 * ns + r;
  const int kb = 32 * kc + 8 * g;
  const float* src = &w1[(size_t)n * DM + kb];
  const float4 v0 = *reinterpret_cast<const float4*>(src);
  const float4 v1 = *reinterpret_cast<const float4*>(src + 4);
  short8 H, M, L;
  split8(v0, v1, H, M, L);
  us* dst = bws + ((size_t)(kc * 4 + ns) * 3) * 512 + l * 8;
  *reinterpret_cast<short8*>(dst) = H;
  *reinterpret_cast<short8*>(dst + 512) = M;
  *reinterpret_cast<short8*>(dst + 1024) = L;
}

// ================= Kernel A (primary): MFMA bf16x3 GEMM ======================
// grid = (TOKENS/128)*SK = 256*4 = 1024 blocks, 4 waves each (3 blocks/CU).
// Wave tile: 32 tokens x 64 experts. No LDS, no barriers.
// Per iter (k=32): 12 B-frag loads (L2), A prefetch for it+1 (HBM latency
// hides under current compute), truncation split (88 VALU), 64 MFMAs
// interleaved 4-wide across independent ns accumulator chains.
#define TMM 128

template <int SK>
__global__ __launch_bounds__(256, 3) void gemm_mfma_kernel(
    const float* __restrict__ x, const us* __restrict__ bws,
    float* __restrict__ hp) {
  constexpr int KS = DM / SK;
  constexpr int NIT = KS / 32;
  const int tid = threadIdx.x;
  const int kz = blockIdx.x % SK;
  const int mb = blockIdx.x / SK;
  const int w = tid >> 6;
  const int l = tid & 63;
  const int r = l & 15, g = l >> 4;
  const int row0 = mb * TMM + w * 32;
  const int kb0 = kz * KS;

  f32x4 acc[2][4];
#pragma unroll
  for (int i = 0; i < 2; ++i)
#pragma unroll
    for (int j = 0; j < 4; ++j) acc[i][j] = (f32x4)(0.f);

  const float* xA0 = &x[(size_t)(row0 + r) * DM + kb0 + 8 * g];
  const float* xA1 = xA0 + (size_t)16 * DM;
  const us* bb = bws + (size_t)(kb0 / 32) * 12 * 512 + l * 8;

  // prologue: A regs for iteration 0
  float4 a00 = *reinterpret_cast<const float4*>(xA0);
  float4 a01 = *reinterpret_cast<const float4*>(xA0 + 4);
  float4 a10 = *reinterpret_cast<const float4*>(xA1);
  float4 a11 = *reinterpret_cast<const float4*>(xA1 + 4);

  for (int it = 0; it < NIT; ++it) {
    // B frags for this iter: 12 coalesced 1KB wave loads (L2-resident)
    const us* bt = bb + (size_t)it * 12 * 512;
    short8 bf[4][3];
#pragma unroll
    for (int ns = 0; ns < 4; ++ns)
#pragma unroll
      for (int p = 0; p < 3; ++p)
        bf[ns][p] =
            *reinterpret_cast<const short8*>(bt + (ns * 3 + p) * 512);

    // A prefetch for next iter (clamped address on last iter; cache-hit)
    const int ko = ((it + 1 < NIT) ? it + 1 : it) * 32;
    const float4 n00 = *reinterpret_cast<const float4*>(xA0 + ko);
    const float4 n01 = *reinterpret_cast<const float4*>(xA0 + ko + 4);
    const float4 n10 = *reinterpret_cast<const float4*>(xA1 + ko);
    const float4 n11 = *reinterpret_cast<const float4*>(xA1 + ko + 4);

    short8 ah, am, al;
    // term order preserved from R4: hh, hm, mh, hl, mm, lh, ml, lm
#define TERMS(H_)                                                        \
  do {                                                                   \
    _Pragma("unroll") for (int ns = 0; ns < 4; ++ns) acc[H_][ns] =       \
        MFMA(ah, bf[ns][0], acc[H_][ns]);                                \
    _Pragma("unroll") for (int ns = 0; ns < 4; ++ns) acc[H_][ns] =       \
        MFMA(ah, bf[ns][1], acc[H_][ns]);                                \
    _Pragma("unroll") for (int ns = 0; ns < 4; ++ns) acc[H_][ns] =       \
        MFMA(am, bf[ns][0], acc[H_][ns]);                                \
    _Pragma("unroll") for (int ns = 0; ns < 4; ++ns) acc[H_][ns] =       \
        MFMA(ah, bf[ns][2], acc[H_][ns]);                                \
    _Pragma("unroll") for (int ns = 0; ns < 4; ++ns) acc[H_][ns] =       \
        MFMA(am, bf[ns][1], acc[H_][ns]);                                \
    _Pragma("unroll") for (int ns = 0; ns < 4; ++ns) acc[H_][ns] =       \
        MFMA(al, bf[ns][0], acc[H_][ns]);                                \
    _Pragma("unroll") for (int ns = 0; ns < 4; ++ns) acc[H_][ns] =       \
        MFMA(am, bf[ns][2], acc[H_][ns]);                                \
    _Pragma("unroll") for (int ns = 0; ns < 4; ++ns) acc[H_][ns] =       \
        MFMA(al, bf[ns][1], acc[H_][ns]);                                \
  } while (0)

    split8t(a00, a01, ah, am, al);
    TERMS(0);
    split8t(a10, a11, ah, am, al);
    TERMS(1);
#undef TERMS

    a00 = n00; a01 = n01; a10 = n10; a11 = n11;
  }

  // C/D layout: col = lane&15, row = 4*(lane>>4) + reg
  float* dst = hp + (size_t)kz * TOKENS * NE;
#pragma unroll
  for (int ms = 0; ms < 2; ++ms)
#pragma unroll
    for (int ns = 0; ns < 4; ++ns)
#pragma unroll
      for (int q = 0; q < 4; ++q)
        dst[(size_t)(row0 + 16 * ms + 4 * g + q) * NE + 16 * ns + r] =
            acc[ms][ns][q];
}

// ================= Kernel A (fallback, proven fp32): 128x64, 4x8/thread =====
#define TM 128
#define BK 32
#define LDSA 132
#define LDSB 68

template <int SK>
__global__ __launch_bounds__(256, 4) void gemm_fp32_kernel(
    const float* __restrict__ x, const float* __restrict__ w1,
    float* __restrict__ hp) {
  constexpr int KS = DM / SK;
  __shared__ float As[BK * LDSA];
  __shared__ float Ws[BK * LDSB];
  const int tid = threadIdx.x;
  const int kz = blockIdx.x % SK;
  const int mb = blockIdx.x / SK;
  const int row0 = mb * TM;
  const int kbase = kz * KS;
  const int m0 = (tid >> 3) * 4;
  const int n0 = (tid & 7) * 8;
  const int rS = tid >> 2;
  const int kS = (tid & 3) * 4;

  float acc[4][8];
#pragma unroll
  for (int i = 0; i < 4; ++i)
#pragma unroll
    for (int j = 0; j < 8; ++j) acc[i][j] = 0.f;

  float4 ra[4], rw[2];
  const float* xp = &x[(size_t)(row0 + rS) * DM + kS];
  const float* wp = &w1[(size_t)rS * DM + kS];

#define LOAD_TILE(KC)                                                   \
  do {                                                                  \
    ra[0] = *reinterpret_cast<const float4*>(xp + (KC));                \
    ra[1] = *reinterpret_cast<const float4*>(xp + (KC) + 16);           \
    ra[2] = *reinterpret_cast<const float4*>(xp + (size_t)64 * DM + (KC));\
    ra[3] = *reinterpret_cast<const float4*>(xp + (size_t)64 * DM + (KC) + 16);\
    rw[0] = *reinterpret_cast<const float4*>(wp + (KC));                \
    rw[1] = *reinterpret_cast<const float4*>(wp + (KC) + 16);           \
  } while (0)

#define ST4(arr, stride, krow, col, v)                                  \
  do {                                                                  \
    arr[((krow) + 0) * (stride) + (col)] = (v).x;                       \
    arr[((krow) + 1) * (stride) + (col)] = (v).y;                       \
    arr[((krow) + 2) * (stride) + (col)] = (v).z;                       \
    arr[((krow) + 3) * (stride) + (col)] = (v).w;                       \
  } while (0)

#define STORE_TILE()                                                    \
  do {                                                                  \
    ST4(As, LDSA, kS, rS, ra[0]);                                       \
    ST4(As, LDSA, kS + 16, rS, ra[1]);                                  \
    ST4(As, LDSA, kS, rS + 64, ra[2]);                                  \
    ST4(As, LDSA, kS + 16, rS + 64, ra[3]);                             \
    ST4(Ws, LDSB, kS, rS, rw[0]);                                       \
    ST4(Ws, LDSB, kS + 16, rS, rw[1]);                                  \
  } while (0)

  LOAD_TILE(kbase);

  for (int kc = kbase; kc < kbase + KS; kc += BK) {
    __syncthreads();
    STORE_TILE();
    __syncthreads();
    if (kc + BK < kbase + KS) LOAD_TILE(kc + BK);
#pragma unroll 8
    for (int k = 0; k < BK; ++k) {
      const float4 a0 = *reinterpret_cast<const float4*>(&As[k * LDSA + m0]);
      const float4 b0 = *reinterpret_cast<const float4*>(&Ws[k * LDSB + n0]);
      const float4 b1 =
          *reinterpret_cast<const float4*>(&Ws[k * LDSB + n0 + 4]);
      const float a[4] = {a0.x, a0.y, a0.z, a0.w};
      const float b[8] = {b0.x, b0.y, b0.z, b0.w, b1.x, b1.y, b1.z, b1.w};
#pragma unroll
      for (int i = 0; i < 4; ++i)
#pragma unroll
        for (int j = 0; j < 8; ++j) acc[i][j] = fmaf(a[i], b[j], acc[i][j]);
    }
  }
#undef LOAD_TILE
#undef ST4
#undef STORE_TILE

  float* dst = hp + (size_t)kz * TOKENS * NE;
#pragma unroll
  for (int i = 0; i < 4; ++i) {
    const size_t o = (size_t)(row0 + m0 + i) * NE;
    *reinterpret_cast<float4*>(&dst[o + n0]) =
        make_float4(acc[i][0], acc[i][1], acc[i][2], acc[i][3]);
    *reinterpret_cast<float4*>(&dst[o + n0 + 4]) =
        make_float4(acc[i][4], acc[i][5], acc[i][6], acc[i][7]);
  }
}

// ================= Kernel B: gate =================
template <int SK>
__global__ __launch_bounds__(256) void gate_kernel(
    const float* __restrict__ hp, const float* __restrict__ w2,
    const float* __restrict__ noise, float* __restrict__ out_idx,
    float* __restrict__ out_score, float* __restrict__ imp_part,
    float* __restrict__ load_part) {
  __shared__ float hs[TG * 65];
  __shared__ float w2s[NE * 65];
  __shared__ float ls[TG * 66];
  __shared__ float csum[2 * NE];
  __shared__ int hist[NE];
  const int tid = threadIdx.x;
  const int t0 = blockIdx.x * TG;
  if (tid < NE) hist[tid] = 0;

#pragma unroll
  for (int it = 0; it < 4; ++it) {
    const int f = tid + 256 * it;
    const int c = f & 15;
    const int t = f >> 4;
    const size_t g = (size_t)(t0 + t) * NE + c * 4;
    float4 p = *reinterpret_cast<const float4*>(&hp[g]);
#pragma unroll
    for (int s = 1; s < SK; ++s) {
      const float4 q =
          *reinterpret_cast<const float4*>(&hp[(size_t)s * TOKENS * NE + g]);
      p.x += q.x; p.y += q.y; p.z += q.z; p.w += q.w;
    }
    float* d = &hs[t * 65 + c * 4];
    d[0] = tanhf(p.x);
    d[1] = tanhf(p.y);
    d[2] = tanhf(p.z);
    d[3] = tanhf(p.w);
  }
#pragma unroll
  for (int it = 0; it < 4; ++it) {
    const int f = tid + 256 * it;
    const int c = f & 15;
    const int rr = f >> 4;
    const float4 v =
        *reinterpret_cast<const float4*>(&w2[(size_t)rr * NE + c * 4]);
    float* d = &w2s[rr * 65 + c * 4];
    d[0] = v.x; d[1] = v.y; d[2] = v.z; d[3] = v.w;
  }
  __syncthreads();

  {
    const int m0 = (tid >> 4) * 4;
    const int n0 = (tid & 15) * 4;
    float acc[4][4];
#pragma unroll
    for (int i = 0; i < 4; ++i)
#pragma unroll
      for (int j = 0; j < 4; ++j) acc[i][j] = 0.f;
#pragma unroll 8
    for (int k = 0; k < NE; ++k) {
      float a[4], b[4];
#pragma unroll
      for (int i = 0; i < 4; ++i) a[i] = hs[(m0 + i) * 65 + k];
#pragma unroll
      for (int j = 0; j < 4; ++j) b[j] = w2s[(n0 + j) * 65 + k];
#pragma unroll
      for (int i = 0; i < 4; ++i)
#pragma unroll
        for (int j = 0; j < 4; ++j) acc[i][j] = fmaf(a[i], b[j], acc[i][j]);
    }
#pragma unroll
    for (int i = 0; i < 4; ++i)
#pragma unroll
      for (int j = 0; j < 4; ++j) ls[(m0 + i) * 66 + n0 + j] = acc[i][j];
  }
  __syncthreads();

  if (tid < TG) {
    const int t = tid;
    float mx = -INFINITY, best = -INFINITY;
    int bi = 0;
    for (int e = 0; e < NE; ++e) {
      const float lv = ls[t * 66 + e];
      mx = fmaxf(mx, lv);
      const float gg = lv + noise[(size_t)(t0 + t) * NE + e];
      if (gg > best) { best = gg; bi = e; }
    }
    float s = 0.f;
    for (int e = 0; e < NE; ++e) {
      const float ex = expf(ls[t * 66 + e] - mx);
      s += ex;
      ls[t * 66 + e] = ex;
    }
    const float inv = 1.f / s;
    for (int e = 0; e < NE; ++e) ls[t * 66 + e] *= inv;
    out_idx[t0 + t] = (float)bi;
    out_score[t0 + t] = best;
    atomicAdd(&hist[bi], 1);
  }
  __syncthreads();

  if (tid < 128) {
    const int e = tid & 63;
    const int half = tid >> 6;
    float s = 0.f;
    for (int rr = half * 32; rr < half * 32 + 32; ++rr) s += ls[rr * 66 + e];
    csum[half * NE + e] = s;
  }
  __syncthreads();
  if (tid < NE) {
    imp_part[(size_t)blockIdx.x * NE + tid] = csum[tid] + csum[NE + tid];
    load_part[(size_t)blockIdx.x * NE + tid] = (float)hist[tid];
  }
}

// ================= Kernel C: finalize =================
__global__ void finalize_kernel(const float* __restrict__ imp_part,
                                const float* __restrict__ load_part,
                                float* __restrict__ out) {
  const int e = threadIdx.x;
  float imp = 0.f, ld = 0.f;
  for (int b = 0; b < GBLOCKS; ++b) {
    imp += imp_part[(size_t)b * NE + e];
    ld += load_part[(size_t)b * NE + e];
  }
  const float imp_mean = imp / (float)TOKENS;
  const float load_mean = ld / (float)TOKENS;
  out[2 * TOKENS + 1 + e] = load_mean;
  out[2 * TOKENS + 1 + NE + e] = imp_mean;
  float prod = imp_mean * load_mean;
#pragma unroll
  for (int off = 32; off > 0; off >>= 1) prod += __shfl_down(prod, off);
  if (e == 0) out[2 * TOKENS] = (float)NE * prod * BALW;
}

// ================= launch =================
extern "C" void kernel_launch(void* const* d_in, const int* in_sizes, int n_in,
                              void* d_out, int out_size, void* d_ws,
                              size_t ws_size, hipStream_t stream) {
  const float* x = (const float*)d_in[0];
  const float* w1 = (const float*)d_in[1];
  const float* w2 = (const float*)d_in[2];
  const float* noise = (const float*)d_in[3];
  float* out = (float*)d_out;

  const size_t bws_shorts = (size_t)128 * 4 * 3 * 512;  // 786432 (1.5 MB)
  const size_t part_elems = (size_t)2 * GBLOCKS * NE;
  const size_t need_mfma = bws_shorts * sizeof(us) +
                           ((size_t)4 * TOKENS * NE + part_elems) *
                               sizeof(float);  // ~35.4 MB
  const size_t need_fp32 =
      ((size_t)2 * TOKENS * NE + part_elems) * sizeof(float);  // ~17 MB

  if (ws_size == 0 || ws_size >= need_mfma) {
    us* bws = (us*)d_ws;
    float* hp = (float*)(bws + bws_shorts);
    float* imp_part = hp + (size_t)4 * TOKENS * NE;
    float* load_part = imp_part + (size_t)GBLOCKS * NE;
    hipLaunchKernelGGL(prep_w1_kernel, dim3(128), dim3(256), 0, stream, w1,
                       bws);
    hipLaunchKernelGGL((gemm_mfma_kernel<4>), dim3((TOKENS / TMM) * 4),
                       dim3(256), 0, stream, x, bws, hp);
    hipLaunchKernelGGL((gate_kernel<4>), dim3(GBLOCKS), dim3(256), 0, stream,
                       hp, w2, noise, out, out + TOKENS, imp_part, load_part);
    hipLaunchKernelGGL(finalize_kernel, dim3(1), dim3(64), 0, stream, imp_part,
                       load_part, out);
  } else if (ws_size >= need_fp32) {
    float* hp = (float*)d_ws;
    float* imp_part = hp + (size_t)2 * TOKENS * NE;
    float* load_part = imp_part + (size_t)GBLOCKS * NE;
    hipLaunchKernelGGL((gemm_fp32_kernel<2>), dim3((TOKENS / TM) * 2),
                       dim3(256), 0, stream, x, w1, hp);
    hipLaunchKernelGGL((gate_kernel<2>), dim3(GBLOCKS), dim3(256), 0, stream,
                       hp, w2, noise, out, out + TOKENS, imp_part, load_part);
    hipLaunchKernelGGL(finalize_kernel, dim3(1), dim3(64), 0, stream, imp_part,
                       load_part, out);
  }
}

// Round 6
// 204.482 us; speedup vs baseline: 1.5761x; 1.0063x over previous
//
#include <hip/hip_runtime.h>
#include <math.h>

// Problem constants
#define TOKENS 32768
#define DM 4096
#define NE 64
#define BALW 0.1f

#define TG 64
#define GBLOCKS (TOKENS / TG)  // 512

typedef __attribute__((ext_vector_type(8))) short short8;   // 8 bf16 = 4 VGPR
typedef __attribute__((ext_vector_type(4))) float f32x4;    // MFMA acc

typedef unsigned short us;

// ---- RNE fp32 -> 3x bf16 split (used in B-prep only; runs once) ----
__device__ inline us bf16r(float f) {
  const unsigned u = __float_as_uint(f);
  return (us)((u + 0x7FFFu + ((u >> 16) & 1u)) >> 16);
}
__device__ inline float bf16f(us s) {
  return __uint_as_float(((unsigned)s) << 16);
}
__device__ inline void split8(const float4 v0, const float4 v1, short8& H,
                              short8& M, short8& L) {
  float v[8] = {v0.x, v0.y, v0.z, v0.w, v1.x, v1.y, v1.z, v1.w};
#pragma unroll
  for (int j = 0; j < 8; ++j) {
    const us hs = bf16r(v[j]);
    const float r1 = v[j] - bf16f(hs);  // exact (Sterbenz)
    const us ms = bf16r(r1);
    const float r2 = r1 - bf16f(ms);    // exact
    const us ls = bf16r(r2);
    H[j] = (short)hs; M[j] = (short)ms; L[j] = (short)ls;
  }
}

// ---- truncation fp32 -> 3x bf16 split (hot path: 44 VALU per 8 elems) ----
__device__ inline void split8t(const float4 v0, const float4 v1, short8& H,
                               short8& M, short8& L) {
  unsigned u[8], um[8], ul[8];
  const float v[8] = {v0.x, v0.y, v0.z, v0.w, v1.x, v1.y, v1.z, v1.w};
#pragma unroll
  for (int j = 0; j < 8; ++j) {
    u[j] = __float_as_uint(v[j]);
    const float r1 = v[j] - __uint_as_float(u[j] & 0xFFFF0000u);
    um[j] = __float_as_uint(r1);
    const float r2 = r1 - __uint_as_float(um[j] & 0xFFFF0000u);
    ul[j] = __float_as_uint(r2);
  }
  union Cvt { unsigned u4[4]; short8 s8; } h, m, l;
#pragma unroll
  for (int d = 0; d < 4; ++d) {
    h.u4[d] = __builtin_amdgcn_perm(u[2 * d + 1], u[2 * d], 0x07060302u);
    m.u4[d] = __builtin_amdgcn_perm(um[2 * d + 1], um[2 * d], 0x07060302u);
    l.u4[d] = __builtin_amdgcn_perm(ul[2 * d + 1], ul[2 * d], 0x07060302u);
  }
  H = h.s8; M = m.s8; L = l.s8;
}

#define MFMA(a, b, c) __builtin_amdgcn_mfma_f32_16x16x32_bf16(a, b, c, 0, 0, 0)

// ================= Kernel P: pre-split w1 into MFMA B-frag order =============
__global__ void prep_w1_kernel(const float* __restrict__ w1,
                               us* __restrict__ bws) {
  const int kc = blockIdx.x;       // 0..127
  const int tid = threadIdx.x;     // 256
  const int ns = tid >> 6;
  const int l = tid & 63;
  const int r = l & 15, g = l >> 4;
  const int n = 16 * ns + r;
  const int kb = 32 * kc + 8 * g;
  const float* src = &w1[(size_t)n * DM + kb];
  const float4 v0 = *reinterpret_cast<const float4*>(src);
  const float4 v1 = *reinterpret_cast<const float4*>(src + 4);
  short8 H, M, L;
  split8(v0, v1, H, M, L);
  us* dst = bws + ((size_t)(kc * 4 + ns) * 3) * 512 + l * 8;
  *reinterpret_cast<short8*>(dst) = H;
  *reinterpret_cast<short8*>(dst + 512) = M;
  *reinterpret_cast<short8*>(dst + 1024) = L;
}

// ================= Kernel A (primary): MFMA bf16x3 GEMM, plane-pipelined =====
// grid = (TOKENS/128)*SK = 1024 blocks, 4 waves each, 3 blocks/CU.
// Wave tile: 32 tokens x 64 experts. No LDS, no barriers.
// Terms ordered by B-plane; bf[*][p] reloaded IN PLACE with next-iter data
// right after its last consumer -> every B load has >=40 MFMAs of cover.
// A prefetched one iter ahead (HBM latency cover).
#define TMM 128

template <int SK>
__global__ __launch_bounds__(256, 3) void gemm_mfma_kernel(
    const float* __restrict__ x, const us* __restrict__ bws,
    float* __restrict__ hp) {
  constexpr int KS = DM / SK;
  constexpr int NIT = KS / 32;
  const int tid = threadIdx.x;
  const int kz = blockIdx.x % SK;
  const int mb = blockIdx.x / SK;
  const int w = tid >> 6;
  const int l = tid & 63;
  const int r = l & 15, g = l >> 4;
  const int row0 = mb * TMM + w * 32;
  const int kb0 = kz * KS;

  f32x4 acc[2][4];
#pragma unroll
  for (int i = 0; i < 2; ++i)
#pragma unroll
    for (int j = 0; j < 4; ++j) acc[i][j] = (f32x4)(0.f);

  const float* xA0 = &x[(size_t)(row0 + r) * DM + kb0 + 8 * g];
  const float* xA1 = xA0 + (size_t)16 * DM;
  const us* bb = bws + (size_t)(kb0 / 32) * 12 * 512 + l * 8;

  // prologue: A and B for iteration 0
  float4 a00 = *reinterpret_cast<const float4*>(xA0);
  float4 a01 = *reinterpret_cast<const float4*>(xA0 + 4);
  float4 a10 = *reinterpret_cast<const float4*>(xA1);
  float4 a11 = *reinterpret_cast<const float4*>(xA1 + 4);
  short8 bf[4][3];
#pragma unroll
  for (int ns = 0; ns < 4; ++ns)
#pragma unroll
    for (int p = 0; p < 3; ++p)
      bf[ns][p] = *reinterpret_cast<const short8*>(bb + (ns * 3 + p) * 512);

  for (int it = 0; it < NIT; ++it) {
    const int itn = (it + 1 < NIT) ? it + 1 : it;  // clamped (last redundant)
    const us* btn = bb + (size_t)itn * 12 * 512;
    const int ko = itn * 32;
    // A prefetch for next iter: full-iteration HBM cover
    const float4 n00 = *reinterpret_cast<const float4*>(xA0 + ko);
    const float4 n01 = *reinterpret_cast<const float4*>(xA0 + ko + 4);
    const float4 n10 = *reinterpret_cast<const float4*>(xA1 + ko);
    const float4 n11 = *reinterpret_cast<const float4*>(xA1 + ko + 4);

    // split both A halves up front (al* die after plane-0 block)
    short8 ah0, am0, al0, ah1, am1, al1;
    split8t(a00, a01, ah0, am0, al0);
    split8t(a10, a11, ah1, am1, al1);

    // 8 MFMAs per A-plane row: all different acc chains (dep distance 8)
#define PROW(AH0, AH1, P)                                                \
  do {                                                                   \
    _Pragma("unroll") for (int ns = 0; ns < 4; ++ns) {                   \
      acc[0][ns] = MFMA(AH0, bf[ns][P], acc[0][ns]);                     \
      acc[1][ns] = MFMA(AH1, bf[ns][P], acc[1][ns]);                     \
    }                                                                    \
  } while (0)
#define RELOAD(P)                                                        \
  do {                                                                   \
    _Pragma("unroll") for (int ns = 0; ns < 4; ++ns) bf[ns][P] =         \
        *reinterpret_cast<const short8*>(btn + (ns * 3 + (P)) * 512);    \
  } while (0)

    // plane 0: terms hh, mh, lh  -> then reload plane 0 for next iter
    PROW(ah0, ah1, 0);
    PROW(am0, am1, 0);
    PROW(al0, al1, 0);
    RELOAD(0);
    // plane 1: terms hm, mm, lm
    PROW(ah0, ah1, 1);
    PROW(am0, am1, 1);
    PROW(al0, al1, 1);
    RELOAD(1);
    // plane 2: terms hl, ml (l*l dropped, ~2^-32)
    PROW(ah0, ah1, 2);
    PROW(am0, am1, 2);
    RELOAD(2);
#undef PROW
#undef RELOAD

    a00 = n00; a01 = n01; a10 = n10; a11 = n11;
  }

  // C/D layout: col = lane&15 (expert), row = 4*(lane>>4) + reg (token)
  float* dst = hp + (size_t)kz * TOKENS * NE;
#pragma unroll
  for (int ms = 0; ms < 2; ++ms)
#pragma unroll
    for (int ns = 0; ns < 4; ++ns)
#pragma unroll
      for (int q = 0; q < 4; ++q)
        dst[(size_t)(row0 + 16 * ms + 4 * g + q) * NE + 16 * ns + r] =
            acc[ms][ns][q];
}

// ================= Kernel A (fallback, proven fp32): 128x64, 4x8/thread =====
#define TM 128
#define BK 32
#define LDSA 132
#define LDSB 68

template <int SK>
__global__ __launch_bounds__(256, 4) void gemm_fp32_kernel(
    const float* __restrict__ x, const float* __restrict__ w1,
    float* __restrict__ hp) {
  constexpr int KS = DM / SK;
  __shared__ float As[BK * LDSA];
  __shared__ float Ws[BK * LDSB];
  const int tid = threadIdx.x;
  const int kz = blockIdx.x % SK;
  const int mb = blockIdx.x / SK;
  const int row0 = mb * TM;
  const int kbase = kz * KS;
  const int m0 = (tid >> 3) * 4;
  const int n0 = (tid & 7) * 8;
  const int rS = tid >> 2;
  const int kS = (tid & 3) * 4;

  float acc[4][8];
#pragma unroll
  for (int i = 0; i < 4; ++i)
#pragma unroll
    for (int j = 0; j < 8; ++j) acc[i][j] = 0.f;

  float4 ra[4], rw[2];
  const float* xp = &x[(size_t)(row0 + rS) * DM + kS];
  const float* wp = &w1[(size_t)rS * DM + kS];

#define LOAD_TILE(KC)                                                   \
  do {                                                                  \
    ra[0] = *reinterpret_cast<const float4*>(xp + (KC));                \
    ra[1] = *reinterpret_cast<const float4*>(xp + (KC) + 16);           \
    ra[2] = *reinterpret_cast<const float4*>(xp + (size_t)64 * DM + (KC));\
    ra[3] = *reinterpret_cast<const float4*>(xp + (size_t)64 * DM + (KC) + 16);\
    rw[0] = *reinterpret_cast<const float4*>(wp + (KC));                \
    rw[1] = *reinterpret_cast<const float4*>(wp + (KC) + 16);           \
  } while (0)

#define ST4(arr, stride, krow, col, v)                                  \
  do {                                                                  \
    arr[((krow) + 0) * (stride) + (col)] = (v).x;                       \
    arr[((krow) + 1) * (stride) + (col)] = (v).y;                       \
    arr[((krow) + 2) * (stride) + (col)] = (v).z;                       \
    arr[((krow) + 3) * (stride) + (col)] = (v).w;                       \
  } while (0)

#define STORE_TILE()                                                    \
  do {                                                                  \
    ST4(As, LDSA, kS, rS, ra[0]);                                       \
    ST4(As, LDSA, kS + 16, rS, ra[1]);                                  \
    ST4(As, LDSA, kS, rS + 64, ra[2]);                                  \
    ST4(As, LDSA, kS + 16, rS + 64, ra[3]);                             \
    ST4(Ws, LDSB, kS, rS, rw[0]);                                       \
    ST4(Ws, LDSB, kS + 16, rS, rw[1]);                                  \
  } while (0)

  LOAD_TILE(kbase);

  for (int kc = kbase; kc < kbase + KS; kc += BK) {
    __syncthreads();
    STORE_TILE();
    __syncthreads();
    if (kc + BK < kbase + KS) LOAD_TILE(kc + BK);
#pragma unroll 8
    for (int k = 0; k < BK; ++k) {
      const float4 a0 = *reinterpret_cast<const float4*>(&As[k * LDSA + m0]);
      const float4 b0 = *reinterpret_cast<const float4*>(&Ws[k * LDSB + n0]);
      const float4 b1 =
          *reinterpret_cast<const float4*>(&Ws[k * LDSB + n0 + 4]);
      const float a[4] = {a0.x, a0.y, a0.z, a0.w};
      const float b[8] = {b0.x, b0.y, b0.z, b0.w, b1.x, b1.y, b1.z, b1.w};
#pragma unroll
      for (int i = 0; i < 4; ++i)
#pragma unroll
        for (int j = 0; j < 8; ++j) acc[i][j] = fmaf(a[i], b[j], acc[i][j]);
    }
  }
#undef LOAD_TILE
#undef ST4
#undef STORE_TILE

  float* dst = hp + (size_t)kz * TOKENS * NE;
#pragma unroll
  for (int i = 0; i < 4; ++i) {
    const size_t o = (size_t)(row0 + m0 + i) * NE;
    *reinterpret_cast<float4*>(&dst[o + n0]) =
        make_float4(acc[i][0], acc[i][1], acc[i][2], acc[i][3]);
    *reinterpret_cast<float4*>(&dst[o + n0 + 4]) =
        make_float4(acc[i][4], acc[i][5], acc[i][6], acc[i][7]);
  }
}

// ================= Kernel B: gate =================
template <int SK>
__global__ __launch_bounds__(256) void gate_kernel(
    const float* __restrict__ hp, const float* __restrict__ w2,
    const float* __restrict__ noise, float* __restrict__ out_idx,
    float* __restrict__ out_score, float* __restrict__ imp_part,
    float* __restrict__ load_part) {
  __shared__ float hs[TG * 65];
  __shared__ float w2s[NE * 65];
  __shared__ float ls[TG * 66];
  __shared__ float csum[2 * NE];
  __shared__ int hist[NE];
  const int tid = threadIdx.x;
  const int t0 = blockIdx.x * TG;
  if (tid < NE) hist[tid] = 0;

#pragma unroll
  for (int it = 0; it < 4; ++it) {
    const int f = tid + 256 * it;
    const int c = f & 15;
    const int t = f >> 4;
    const size_t g = (size_t)(t0 + t) * NE + c * 4;
    float4 p = *reinterpret_cast<const float4*>(&hp[g]);
#pragma unroll
    for (int s = 1; s < SK; ++s) {
      const float4 q =
          *reinterpret_cast<const float4*>(&hp[(size_t)s * TOKENS * NE + g]);
      p.x += q.x; p.y += q.y; p.z += q.z; p.w += q.w;
    }
    float* d = &hs[t * 65 + c * 4];
    d[0] = tanhf(p.x);
    d[1] = tanhf(p.y);
    d[2] = tanhf(p.z);
    d[3] = tanhf(p.w);
  }
#pragma unroll
  for (int it = 0; it < 4; ++it) {
    const int f = tid + 256 * it;
    const int c = f & 15;
    const int rr = f >> 4;
    const float4 v =
        *reinterpret_cast<const float4*>(&w2[(size_t)rr * NE + c * 4]);
    float* d = &w2s[rr * 65 + c * 4];
    d[0] = v.x; d[1] = v.y; d[2] = v.z; d[3] = v.w;
  }
  __syncthreads();

  {
    const int m0 = (tid >> 4) * 4;
    const int n0 = (tid & 15) * 4;
    float acc[4][4];
#pragma unroll
    for (int i = 0; i < 4; ++i)
#pragma unroll
      for (int j = 0; j < 4; ++j) acc[i][j] = 0.f;
#pragma unroll 8
    for (int k = 0; k < NE; ++k) {
      float a[4], b[4];
#pragma unroll
      for (int i = 0; i < 4; ++i) a[i] = hs[(m0 + i) * 65 + k];
#pragma unroll
      for (int j = 0; j < 4; ++j) b[j] = w2s[(n0 + j) * 65 + k];
#pragma unroll
      for (int i = 0; i < 4; ++i)
#pragma unroll
        for (int j = 0; j < 4; ++j) acc[i][j] = fmaf(a[i], b[j], acc[i][j]);
    }
#pragma unroll
    for (int i = 0; i < 4; ++i)
#pragma unroll
      for (int j = 0; j < 4; ++j) ls[(m0 + i) * 66 + n0 + j] = acc[i][j];
  }
  __syncthreads();

  if (tid < TG) {
    const int t = tid;
    float mx = -INFINITY, best = -INFINITY;
    int bi = 0;
    for (int e = 0; e < NE; ++e) {
      const float lv = ls[t * 66 + e];
      mx = fmaxf(mx, lv);
      const float gg = lv + noise[(size_t)(t0 + t) * NE + e];
      if (gg > best) { best = gg; bi = e; }
    }
    float s = 0.f;
    for (int e = 0; e < NE; ++e) {
      const float ex = expf(ls[t * 66 + e] - mx);
      s += ex;
      ls[t * 66 + e] = ex;
    }
    const float inv = 1.f / s;
    for (int e = 0; e < NE; ++e) ls[t * 66 + e] *= inv;
    out_idx[t0 + t] = (float)bi;
    out_score[t0 + t] = best;
    atomicAdd(&hist[bi], 1);
  }
  __syncthreads();

  if (tid < 128) {
    const int e = tid & 63;
    const int half = tid >> 6;
    float s = 0.f;
    for (int rr = half * 32; rr < half * 32 + 32; ++rr) s += ls[rr * 66 + e];
    csum[half * NE + e] = s;
  }
  __syncthreads();
  if (tid < NE) {
    imp_part[(size_t)blockIdx.x * NE + tid] = csum[tid] + csum[NE + tid];
    load_part[(size_t)blockIdx.x * NE + tid] = (float)hist[tid];
  }
}

// ================= Kernel C: finalize =================
__global__ void finalize_kernel(const float* __restrict__ imp_part,
                                const float* __restrict__ load_part,
                                float* __restrict__ out) {
  const int e = threadIdx.x;
  float imp = 0.f, ld = 0.f;
  for (int b = 0; b < GBLOCKS; ++b) {
    imp += imp_part[(size_t)b * NE + e];
    ld += load_part[(size_t)b * NE + e];
  }
  const float imp_mean = imp / (float)TOKENS;
  const float load_mean = ld / (float)TOKENS;
  out[2 * TOKENS + 1 + e] = load_mean;
  out[2 * TOKENS + 1 + NE + e] = imp_mean;
  float prod = imp_mean * load_mean;
#pragma unroll
  for (int off = 32; off > 0; off >>= 1) prod += __shfl_down(prod, off);
  if (e == 0) out[2 * TOKENS] = (float)NE * prod * BALW;
}

// ================= launch =================
extern "C" void kernel_launch(void* const* d_in, const int* in_sizes, int n_in,
                              void* d_out, int out_size, void* d_ws,
                              size_t ws_size, hipStream_t stream) {
  const float* x = (const float*)d_in[0];
  const float* w1 = (const float*)d_in[1];
  const float* w2 = (const float*)d_in[2];
  const float* noise = (const float*)d_in[3];
  float* out = (float*)d_out;

  const size_t bws_shorts = (size_t)128 * 4 * 3 * 512;  // 786432 (1.5 MB)
  const size_t part_elems = (size_t)2 * GBLOCKS * NE;
  const size_t need_mfma = bws_shorts * sizeof(us) +
                           ((size_t)4 * TOKENS * NE + part_elems) *
                               sizeof(float);  // ~35.4 MB
  const size_t need_fp32 =
      ((size_t)2 * TOKENS * NE + part_elems) * sizeof(float);  // ~17 MB

  if (ws_size == 0 || ws_size >= need_mfma) {
    us* bws = (us*)d_ws;
    float* hp = (float*)(bws + bws_shorts);
    float* imp_part = hp + (size_t)4 * TOKENS * NE;
    float* load_part = imp_part + (size_t)GBLOCKS * NE;
    hipLaunchKernelGGL(prep_w1_kernel, dim3(128), dim3(256), 0, stream, w1,
                       bws);
    hipLaunchKernelGGL((gemm_mfma_kernel<4>), dim3((TOKENS / TMM) * 4),
                       dim3(256), 0, stream, x, bws, hp);
    hipLaunchKernelGGL((gate_kernel<4>), dim3(GBLOCKS), dim3(256), 0, stream,
                       hp, w2, noise, out, out + TOKENS, imp_part, load_part);
    hipLaunchKernelGGL(finalize_kernel, dim3(1), dim3(64), 0, stream, imp_part,
                       load_part, out);
  } else if (ws_size >= need_fp32) {
    float* hp = (float*)d_ws;
    float* imp_part = hp + (size_t)2 * TOKENS * NE;
    float* load_part = imp_part + (size_t)GBLOCKS * NE;
    hipLaunchKernelGGL((gemm_fp32_kernel<2>), dim3((TOKENS / TM) * 2),
                       dim3(256), 0, stream, x, w1, hp);
    hipLaunchKernelGGL((gate_kernel<2>), dim3(GBLOCKS), dim3(256), 0, stream,
                       hp, w2, noise, out, out + TOKENS, imp_part, load_part);
    hipLaunchKernelGGL(finalize_kernel, dim3(1), dim3(64), 0, stream, imp_part,
                       load_part, out);
  }
}

// Round 7
// 202.341 us; speedup vs baseline: 1.5928x; 1.0106x over previous
//
#include <hip/hip_runtime.h>
#include <math.h>

// Problem constants
#define TOKENS 32768
#define DM 4096
#define NE 64
#define BALW 0.1f

#define TG 64
#define GBLOCKS (TOKENS / TG)  // 512

typedef __attribute__((ext_vector_type(8))) short short8;   // 8 bf16 = 4 VGPR
typedef __attribute__((ext_vector_type(4))) float f32x4;    // MFMA acc

typedef unsigned short us;

// ---- RNE fp32 -> 3x bf16 split (used in B-prep only; runs once) ----
__device__ inline us bf16r(float f) {
  const unsigned u = __float_as_uint(f);
  return (us)((u + 0x7FFFu + ((u >> 16) & 1u)) >> 16);
}
__device__ inline float bf16f(us s) {
  return __uint_as_float(((unsigned)s) << 16);
}
__device__ inline void split8(const float4 v0, const float4 v1, short8& H,
                              short8& M, short8& L) {
  float v[8] = {v0.x, v0.y, v0.z, v0.w, v1.x, v1.y, v1.z, v1.w};
#pragma unroll
  for (int j = 0; j < 8; ++j) {
    const us hs = bf16r(v[j]);
    const float r1 = v[j] - bf16f(hs);  // exact (Sterbenz)
    const us ms = bf16r(r1);
    const float r2 = r1 - bf16f(ms);    // exact
    const us ls = bf16r(r2);
    H[j] = (short)hs; M[j] = (short)ms; L[j] = (short)ls;
  }
}

// ---- truncation fp32 -> 3x bf16 split (hot path: 44 VALU per 8 elems) ----
__device__ inline void split8t(const float4 v0, const float4 v1, short8& H,
                               short8& M, short8& L) {
  unsigned u[8], um[8], ul[8];
  const float v[8] = {v0.x, v0.y, v0.z, v0.w, v1.x, v1.y, v1.z, v1.w};
#pragma unroll
  for (int j = 0; j < 8; ++j) {
    u[j] = __float_as_uint(v[j]);
    const float r1 = v[j] - __uint_as_float(u[j] & 0xFFFF0000u);
    um[j] = __float_as_uint(r1);
    const float r2 = r1 - __uint_as_float(um[j] & 0xFFFF0000u);
    ul[j] = __float_as_uint(r2);
  }
  union Cvt { unsigned u4[4]; short8 s8; } h, m, l;
#pragma unroll
  for (int d = 0; d < 4; ++d) {
    h.u4[d] = __builtin_amdgcn_perm(u[2 * d + 1], u[2 * d], 0x07060302u);
    m.u4[d] = __builtin_amdgcn_perm(um[2 * d + 1], um[2 * d], 0x07060302u);
    l.u4[d] = __builtin_amdgcn_perm(ul[2 * d + 1], ul[2 * d], 0x07060302u);
  }
  H = h.s8; M = m.s8; L = l.s8;
}

#define MFMA(a, b, c) __builtin_amdgcn_mfma_f32_16x16x32_bf16(a, b, c, 0, 0, 0)

// ================= Kernel P: pre-split w1 into MFMA B-frag order =============
__global__ void prep_w1_kernel(const float* __restrict__ w1,
                               us* __restrict__ bws) {
  const int kc = blockIdx.x;       // 0..127
  const int tid = threadIdx.x;     // 256
  const int ns = tid >> 6;
  const int l = tid & 63;
  const int r = l & 15, g = l >> 4;
  const int n = 16 * ns + r;
  const int kb = 32 * kc + 8 * g;
  const float* src = &w1[(size_t)n * DM + kb];
  const float4 v0 = *reinterpret_cast<const float4*>(src);
  const float4 v1 = *reinterpret_cast<const float4*>(src + 4);
  short8 H, M, L;
  split8(v0, v1, H, M, L);
  us* dst = bws + ((size_t)(kc * 4 + ns) * 3) * 512 + l * 8;
  *reinterpret_cast<short8*>(dst) = H;
  *reinterpret_cast<short8*>(dst + 512) = M;
  *reinterpret_cast<short8*>(dst + 1024) = L;
}

// ================= Kernel A (primary): MFMA bf16x3 GEMM, 6-term ==============
// SK=2: grid = (TOKENS/128)*2 = 512 blocks, 4 waves each -> EXACTLY 2
// blocks/CU (zero occupancy tail; the SK=4/1024-block variant left a
// 256-block tail at 1 block/CU). Wave tile: 32 tokens x 64 experts.
// No LDS, no barriers. 6 product terms (hh,hm,mh,mm,hl,lh); dropped ml+lm
// contribute ~2^-24 rel (~1e-7 on logits) -- below fp32 accumulation noise.
// B planes reloaded in place after last consumer; A prefetched 1 iter ahead.
#define TMM 128

template <int SK>
__global__ __launch_bounds__(256, 2) void gemm_mfma_kernel(
    const float* __restrict__ x, const us* __restrict__ bws,
    float* __restrict__ hp) {
  constexpr int KS = DM / SK;
  constexpr int NIT = KS / 32;
  const int tid = threadIdx.x;
  const int kz = blockIdx.x % SK;
  const int mb = blockIdx.x / SK;
  const int w = tid >> 6;
  const int l = tid & 63;
  const int r = l & 15, g = l >> 4;
  const int row0 = mb * TMM + w * 32;
  const int kb0 = kz * KS;

  f32x4 acc[2][4];
#pragma unroll
  for (int i = 0; i < 2; ++i)
#pragma unroll
    for (int j = 0; j < 4; ++j) acc[i][j] = (f32x4)(0.f);

  const float* xA0 = &x[(size_t)(row0 + r) * DM + kb0 + 8 * g];
  const float* xA1 = xA0 + (size_t)16 * DM;
  const us* bb = bws + (size_t)(kb0 / 32) * 12 * 512 + l * 8;

  // prologue: A and B for iteration 0
  float4 a00 = *reinterpret_cast<const float4*>(xA0);
  float4 a01 = *reinterpret_cast<const float4*>(xA0 + 4);
  float4 a10 = *reinterpret_cast<const float4*>(xA1);
  float4 a11 = *reinterpret_cast<const float4*>(xA1 + 4);
  short8 bf[4][3];
#pragma unroll
  for (int ns = 0; ns < 4; ++ns)
#pragma unroll
    for (int p = 0; p < 3; ++p)
      bf[ns][p] = *reinterpret_cast<const short8*>(bb + (ns * 3 + p) * 512);

  for (int it = 0; it < NIT; ++it) {
    const int itn = (it + 1 < NIT) ? it + 1 : it;  // clamped (last redundant)
    const us* btn = bb + (size_t)itn * 12 * 512;
    const int ko = itn * 32;
    // A prefetch for next iter: full-iteration HBM cover
    const float4 n00 = *reinterpret_cast<const float4*>(xA0 + ko);
    const float4 n01 = *reinterpret_cast<const float4*>(xA0 + ko + 4);
    const float4 n10 = *reinterpret_cast<const float4*>(xA1 + ko);
    const float4 n11 = *reinterpret_cast<const float4*>(xA1 + ko + 4);

    short8 ah0, am0, al0, ah1, am1, al1;
    split8t(a00, a01, ah0, am0, al0);
    split8t(a10, a11, ah1, am1, al1);

#define PROW(AH0, AH1, P)                                                \
  do {                                                                   \
    _Pragma("unroll") for (int ns = 0; ns < 4; ++ns) {                   \
      acc[0][ns] = MFMA(AH0, bf[ns][P], acc[0][ns]);                     \
      acc[1][ns] = MFMA(AH1, bf[ns][P], acc[1][ns]);                     \
    }                                                                    \
  } while (0)
#define RELOAD(P)                                                        \
  do {                                                                   \
    _Pragma("unroll") for (int ns = 0; ns < 4; ++ns) bf[ns][P] =         \
        *reinterpret_cast<const short8*>(btn + (ns * 3 + (P)) * 512);    \
  } while (0)

    // plane 0 (b_h): terms hh, mh, lh
    PROW(ah0, ah1, 0);
    PROW(am0, am1, 0);
    PROW(al0, al1, 0);
    RELOAD(0);
    // plane 1 (b_m): terms hm, mm
    PROW(ah0, ah1, 1);
    PROW(am0, am1, 1);
    RELOAD(1);
    // plane 2 (b_l): term hl   (ml, lm, ll dropped: ~2^-24 rel)
    PROW(ah0, ah1, 2);
    RELOAD(2);
#undef PROW
#undef RELOAD

    a00 = n00; a01 = n01; a10 = n10; a11 = n11;
  }

  // C/D layout: col = lane&15 (expert), row = 4*(lane>>4) + reg (token)
  float* dst = hp + (size_t)kz * TOKENS * NE;
#pragma unroll
  for (int ms = 0; ms < 2; ++ms)
#pragma unroll
    for (int ns = 0; ns < 4; ++ns)
#pragma unroll
      for (int q = 0; q < 4; ++q)
        dst[(size_t)(row0 + 16 * ms + 4 * g + q) * NE + 16 * ns + r] =
            acc[ms][ns][q];
}

// ================= Kernel A (fallback, proven fp32): 128x64, 4x8/thread =====
#define TM 128
#define BK 32
#define LDSA 132
#define LDSB 68

template <int SK>
__global__ __launch_bounds__(256, 4) void gemm_fp32_kernel(
    const float* __restrict__ x, const float* __restrict__ w1,
    float* __restrict__ hp) {
  constexpr int KS = DM / SK;
  __shared__ float As[BK * LDSA];
  __shared__ float Ws[BK * LDSB];
  const int tid = threadIdx.x;
  const int kz = blockIdx.x % SK;
  const int mb = blockIdx.x / SK;
  const int row0 = mb * TM;
  const int kbase = kz * KS;
  const int m0 = (tid >> 3) * 4;
  const int n0 = (tid & 7) * 8;
  const int rS = tid >> 2;
  const int kS = (tid & 3) * 4;

  float acc[4][8];
#pragma unroll
  for (int i = 0; i < 4; ++i)
#pragma unroll
    for (int j = 0; j < 8; ++j) acc[i][j] = 0.f;

  float4 ra[4], rw[2];
  const float* xp = &x[(size_t)(row0 + rS) * DM + kS];
  const float* wp = &w1[(size_t)rS * DM + kS];

#define LOAD_TILE(KC)                                                   \
  do {                                                                  \
    ra[0] = *reinterpret_cast<const float4*>(xp + (KC));                \
    ra[1] = *reinterpret_cast<const float4*>(xp + (KC) + 16);           \
    ra[2] = *reinterpret_cast<const float4*>(xp + (size_t)64 * DM + (KC));\
    ra[3] = *reinterpret_cast<const float4*>(xp + (size_t)64 * DM + (KC) + 16);\
    rw[0] = *reinterpret_cast<const float4*>(wp + (KC));                \
    rw[1] = *reinterpret_cast<const float4*>(wp + (KC) + 16);           \
  } while (0)

#define ST4(arr, stride, krow, col, v)                                  \
  do {                                                                  \
    arr[((krow) + 0) * (stride) + (col)] = (v).x;                       \
    arr[((krow) + 1) * (stride) + (col)] = (v).y;                       \
    arr[((krow) + 2) * (stride) + (col)] = (v).z;                       \
    arr[((krow) + 3) * (stride) + (col)] = (v).w;                       \
  } while (0)

#define STORE_TILE()                                                    \
  do {                                                                  \
    ST4(As, LDSA, kS, rS, ra[0]);                                       \
    ST4(As, LDSA, kS + 16, rS, ra[1]);                                  \
    ST4(As, LDSA, kS, rS + 64, ra[2]);                                  \
    ST4(As, LDSA, kS + 16, rS + 64, ra[3]);                             \
    ST4(Ws, LDSB, kS, rS, rw[0]);                                       \
    ST4(Ws, LDSB, kS + 16, rS, rw[1]);                                  \
  } while (0)

  LOAD_TILE(kbase);

  for (int kc = kbase; kc < kbase + KS; kc += BK) {
    __syncthreads();
    STORE_TILE();
    __syncthreads();
    if (kc + BK < kbase + KS) LOAD_TILE(kc + BK);
#pragma unroll 8
    for (int k = 0; k < BK; ++k) {
      const float4 a0 = *reinterpret_cast<const float4*>(&As[k * LDSA + m0]);
      const float4 b0 = *reinterpret_cast<const float4*>(&Ws[k * LDSB + n0]);
      const float4 b1 =
          *reinterpret_cast<const float4*>(&Ws[k * LDSB + n0 + 4]);
      const float a[4] = {a0.x, a0.y, a0.z, a0.w};
      const float b[8] = {b0.x, b0.y, b0.z, b0.w, b1.x, b1.y, b1.z, b1.w};
#pragma unroll
      for (int i = 0; i < 4; ++i)
#pragma unroll
        for (int j = 0; j < 8; ++j) acc[i][j] = fmaf(a[i], b[j], acc[i][j]);
    }
  }
#undef LOAD_TILE
#undef ST4
#undef STORE_TILE

  float* dst = hp + (size_t)kz * TOKENS * NE;
#pragma unroll
  for (int i = 0; i < 4; ++i) {
    const size_t o = (size_t)(row0 + m0 + i) * NE;
    *reinterpret_cast<float4*>(&dst[o + n0]) =
        make_float4(acc[i][0], acc[i][1], acc[i][2], acc[i][3]);
    *reinterpret_cast<float4*>(&dst[o + n0 + 4]) =
        make_float4(acc[i][4], acc[i][5], acc[i][6], acc[i][7]);
  }
}

// ================= Kernel B: gate =================
template <int SK>
__global__ __launch_bounds__(256) void gate_kernel(
    const float* __restrict__ hp, const float* __restrict__ w2,
    const float* __restrict__ noise, float* __restrict__ out_idx,
    float* __restrict__ out_score, float* __restrict__ imp_part,
    float* __restrict__ load_part) {
  __shared__ float hs[TG * 65];
  __shared__ float w2s[NE * 65];
  __shared__ float ls[TG * 66];
  __shared__ float csum[2 * NE];
  __shared__ int hist[NE];
  const int tid = threadIdx.x;
  const int t0 = blockIdx.x * TG;
  if (tid < NE) hist[tid] = 0;

#pragma unroll
  for (int it = 0; it < 4; ++it) {
    const int f = tid + 256 * it;
    const int c = f & 15;
    const int t = f >> 4;
    const size_t g = (size_t)(t0 + t) * NE + c * 4;
    float4 p = *reinterpret_cast<const float4*>(&hp[g]);
#pragma unroll
    for (int s = 1; s < SK; ++s) {
      const float4 q =
          *reinterpret_cast<const float4*>(&hp[(size_t)s * TOKENS * NE + g]);
      p.x += q.x; p.y += q.y; p.z += q.z; p.w += q.w;
    }
    float* d = &hs[t * 65 + c * 4];
    d[0] = tanhf(p.x);
    d[1] = tanhf(p.y);
    d[2] = tanhf(p.z);
    d[3] = tanhf(p.w);
  }
#pragma unroll
  for (int it = 0; it < 4; ++it) {
    const int f = tid + 256 * it;
    const int c = f & 15;
    const int rr = f >> 4;
    const float4 v =
        *reinterpret_cast<const float4*>(&w2[(size_t)rr * NE + c * 4]);
    float* d = &w2s[rr * 65 + c * 4];
    d[0] = v.x; d[1] = v.y; d[2] = v.z; d[3] = v.w;
  }
  __syncthreads();

  {
    const int m0 = (tid >> 4) * 4;
    const int n0 = (tid & 15) * 4;
    float acc[4][4];
#pragma unroll
    for (int i = 0; i < 4; ++i)
#pragma unroll
      for (int j = 0; j < 4; ++j) acc[i][j] = 0.f;
#pragma unroll 8
    for (int k = 0; k < NE; ++k) {
      float a[4], b[4];
#pragma unroll
      for (int i = 0; i < 4; ++i) a[i] = hs[(m0 + i) * 65 + k];
#pragma unroll
      for (int j = 0; j < 4; ++j) b[j] = w2s[(n0 + j) * 65 + k];
#pragma unroll
      for (int i = 0; i < 4; ++i)
#pragma unroll
        for (int j = 0; j < 4; ++j) acc[i][j] = fmaf(a[i], b[j], acc[i][j]);
    }
#pragma unroll
    for (int i = 0; i < 4; ++i)
#pragma unroll
      for (int j = 0; j < 4; ++j) ls[(m0 + i) * 66 + n0 + j] = acc[i][j];
  }
  __syncthreads();

  if (tid < TG) {
    const int t = tid;
    float mx = -INFINITY, best = -INFINITY;
    int bi = 0;
    for (int e = 0; e < NE; ++e) {
      const float lv = ls[t * 66 + e];
      mx = fmaxf(mx, lv);
      const float gg = lv + noise[(size_t)(t0 + t) * NE + e];
      if (gg > best) { best = gg; bi = e; }
    }
    float s = 0.f;
    for (int e = 0; e < NE; ++e) {
      const float ex = expf(ls[t * 66 + e] - mx);
      s += ex;
      ls[t * 66 + e] = ex;
    }
    const float inv = 1.f / s;
    for (int e = 0; e < NE; ++e) ls[t * 66 + e] *= inv;
    out_idx[t0 + t] = (float)bi;
    out_score[t0 + t] = best;
    atomicAdd(&hist[bi], 1);
  }
  __syncthreads();

  if (tid < 128) {
    const int e = tid & 63;
    const int half = tid >> 6;
    float s = 0.f;
    for (int rr = half * 32; rr < half * 32 + 32; ++rr) s += ls[rr * 66 + e];
    csum[half * NE + e] = s;
  }
  __syncthreads();
  if (tid < NE) {
    imp_part[(size_t)blockIdx.x * NE + tid] = csum[tid] + csum[NE + tid];
    load_part[(size_t)blockIdx.x * NE + tid] = (float)hist[tid];
  }
}

// ================= Kernel C: finalize =================
__global__ void finalize_kernel(const float* __restrict__ imp_part,
                                const float* __restrict__ load_part,
                                float* __restrict__ out) {
  const int e = threadIdx.x;
  float imp = 0.f, ld = 0.f;
  for (int b = 0; b < GBLOCKS; ++b) {
    imp += imp_part[(size_t)b * NE + e];
    ld += load_part[(size_t)b * NE + e];
  }
  const float imp_mean = imp / (float)TOKENS;
  const float load_mean = ld / (float)TOKENS;
  out[2 * TOKENS + 1 + e] = load_mean;
  out[2 * TOKENS + 1 + NE + e] = imp_mean;
  float prod = imp_mean * load_mean;
#pragma unroll
  for (int off = 32; off > 0; off >>= 1) prod += __shfl_down(prod, off);
  if (e == 0) out[2 * TOKENS] = (float)NE * prod * BALW;
}

// ================= launch =================
extern "C" void kernel_launch(void* const* d_in, const int* in_sizes, int n_in,
                              void* d_out, int out_size, void* d_ws,
                              size_t ws_size, hipStream_t stream) {
  const float* x = (const float*)d_in[0];
  const float* w1 = (const float*)d_in[1];
  const float* w2 = (const float*)d_in[2];
  const float* noise = (const float*)d_in[3];
  float* out = (float*)d_out;

  const size_t bws_shorts = (size_t)128 * 4 * 3 * 512;  // 786432 (1.5 MB)
  const size_t part_elems = (size_t)2 * GBLOCKS * NE;
  const size_t need_mfma = bws_shorts * sizeof(us) +
                           ((size_t)2 * TOKENS * NE + part_elems) *
                               sizeof(float);  // ~18.6 MB
  const size_t need_fp32 =
      ((size_t)2 * TOKENS * NE + part_elems) * sizeof(float);  // ~17 MB

  if (ws_size == 0 || ws_size >= need_mfma) {
    us* bws = (us*)d_ws;
    float* hp = (float*)(bws + bws_shorts);
    float* imp_part = hp + (size_t)2 * TOKENS * NE;
    float* load_part = imp_part + (size_t)GBLOCKS * NE;
    hipLaunchKernelGGL(prep_w1_kernel, dim3(128), dim3(256), 0, stream, w1,
                       bws);
    hipLaunchKernelGGL((gemm_mfma_kernel<2>), dim3((TOKENS / TMM) * 2),
                       dim3(256), 0, stream, x, bws, hp);
    hipLaunchKernelGGL((gate_kernel<2>), dim3(GBLOCKS), dim3(256), 0, stream,
                       hp, w2, noise, out, out + TOKENS, imp_part, load_part);
    hipLaunchKernelGGL(finalize_kernel, dim3(1), dim3(64), 0, stream, imp_part,
                       load_part, out);
  } else if (ws_size >= need_fp32) {
    float* hp = (float*)d_ws;
    float* imp_part = hp + (size_t)2 * TOKENS * NE;
    float* load_part = imp_part + (size_t)GBLOCKS * NE;
    hipLaunchKernelGGL((gemm_fp32_kernel<2>), dim3((TOKENS / TM) * 2),
                       dim3(256), 0, stream, x, w1, hp);
    hipLaunchKernelGGL((gate_kernel<2>), dim3(GBLOCKS), dim3(256), 0, stream,
                       hp, w2, noise, out, out + TOKENS, imp_part, load_part);
    hipLaunchKernelGGL(finalize_kernel, dim3(1), dim3(64), 0, stream, imp_part,
                       load_part, out);
  }
}